// Round 1
// baseline (1699.108 us; speedup 1.0000x reference)
//
#include <hip/hip_runtime.h>
#include <math.h>

#define B_ 16
#define C_ 129
#define T_ 2000
#define NF_ 40
#define ED_ 64
#define K_ 16
#define TP_ 500

// workspace float offsets
#define OFF_W1C 0        // 1000  tconv weights * tbn scale
#define OFF_TB2 1000     // 40    folded tconv bias
#define OFF_SB2 1040     // 40    folded sconv bias
#define OFF_PWC 1088     // 3200  pw weights * pbn scale
#define OFF_PB2 4288     // 80    folded pw bias
#define OFF_WP  4368     // 1280  wx0 @ proj_w  (16x80)
#define OFF_BP  5648     // 16    wx0 @ proj_b + b0
#define OFF_M0  5664     // 256   L0@L0.T - exp(ll0) I
#define OFF_M1  5920     // 256   L1@L1.T - exp(ll1) I
#define OFF_W2U 8192     // 206400 repacked sconv weights [c][ghalf][f][20] * sbn scale
#define OFF_S2  215040   // 16*40*2000 fused conv-stack output
#define OFF_XP  1495040  // 16*500*16  per-step cell0 input projection

__device__ __forceinline__ float elu_f(float x) {
    return x > 0.f ? x : (__expf(x) - 1.f);
}
__device__ __forceinline__ float tanh_f(float x) {
    float xc = fminf(fmaxf(x, -15.f), 15.f);
    float e2 = __expf(2.f * xc);
    return 1.f - 2.f / (e2 + 1.f);
}

struct P0 {
    const float *tconv_w, *tconv_b, *tbn_g, *tbn_b, *tbn_m, *tbn_v;
    const float *sconv_b, *sbn_g, *sbn_b, *sbn_m, *sbn_v;
    const float *pw_w, *pw_b, *pbn_g, *pbn_b, *pbn_m, *pbn_v;
    const float *proj_w, *proj_b, *wx0, *b0, *L0, *ll0, *L1, *ll1;
    float* ws;
};

__global__ __launch_bounds__(256) void k0a_setup(P0 p) {
    const int tid = threadIdx.x;
    float* ws = p.ws;
    const float eps = 1e-5f;
    for (int e = tid; e < 1000; e += 256) {
        const int f = e / 25;
        const float inv = p.tbn_g[f] / sqrtf(p.tbn_v[f] + eps);
        ws[OFF_W1C + e] = p.tconv_w[e] * inv;
    }
    for (int f = tid; f < NF_; f += 256) {
        const float inv = p.tbn_g[f] / sqrtf(p.tbn_v[f] + eps);
        ws[OFF_TB2 + f] = p.tconv_b[f] * inv + p.tbn_b[f] - p.tbn_m[f] * inv;
        const float sinv = p.sbn_g[f] / sqrtf(p.sbn_v[f] + eps);
        ws[OFF_SB2 + f] = p.sconv_b[f] * sinv + p.sbn_b[f] - p.sbn_m[f] * sinv;
    }
    for (int e = tid; e < 3200; e += 256) {
        const int g = e / 40;
        const float pinv = p.pbn_g[g] / sqrtf(p.pbn_v[g] + eps);
        ws[OFF_PWC + e] = p.pw_w[e] * pinv;
    }
    for (int g = tid; g < 80; g += 256) {
        const float pinv = p.pbn_g[g] / sqrtf(p.pbn_v[g] + eps);
        ws[OFF_PB2 + g] = p.pw_b[g] * pinv + p.pbn_b[g] - p.pbn_m[g] * pinv;
    }
    for (int e = tid; e < 1280; e += 256) {
        const int k = e / 80, g = e - k * 80;
        float a = 0.f;
        for (int ee = 0; ee < ED_; ++ee)
            a = fmaf(p.wx0[k * ED_ + ee], p.proj_w[ee * 80 + g], a);
        ws[OFF_WP + e] = a;
    }
    for (int k = tid; k < K_; k += 256) {
        float a = p.b0[k];
        for (int ee = 0; ee < ED_; ++ee)
            a = fmaf(p.wx0[k * ED_ + ee], p.proj_b[ee], a);
        ws[OFF_BP + k] = a;
    }
    for (int e = tid; e < 256; e += 256) {
        const int k = e >> 4, j = e & 15;
        float a0 = 0.f, a1 = 0.f;
        for (int i = 0; i < 16; ++i) {
            a0 = fmaf(p.L0[k * 16 + i], p.L0[j * 16 + i], a0);
            a1 = fmaf(p.L1[k * 16 + i], p.L1[j * 16 + i], a1);
        }
        if (k == j) { a0 -= expf(p.ll0[0]); a1 -= expf(p.ll1[0]); }
        ws[OFF_M0 + e] = a0;
        ws[OFF_M1 + e] = a1;
    }
}

// repack sconv_w[g][f][c] -> w2u[c][ghalf][f][j], scaled by sbn inv
__global__ __launch_bounds__(256) void k0b_repack(
    const float* __restrict__ sconv_w, const float* __restrict__ sbn_g,
    const float* __restrict__ sbn_v, float* __restrict__ w2u) {
    const int total = C_ * 1600;
    for (int e = blockIdx.x * 256 + threadIdx.x; e < total; e += 256 * 256) {
        const int c = e / 1600;
        int r = e - c * 1600;
        const int gh = r / 800; r -= gh * 800;
        const int f = r / 20;
        const int j = r - f * 20;
        const int g = gh * 20 + j;
        const float sinv = sbn_g[g] / sqrtf(sbn_v[g] + 1e-5f);
        w2u[e] = sconv_w[g * (NF_ * C_) + f * C_ + c] * sinv;
    }
}

// Fused: tconv(25) + BN + ELU + sconv(40x40x129) + BN + ELU -> s2[b][g][t]
__global__ __launch_bounds__(256) void k1_conv(
    const float* __restrict__ x, const float* __restrict__ w1c,
    const float* __restrict__ tb2, const float* __restrict__ w2u,
    const float* __restrict__ sb2, float* __restrict__ s2) {
    __shared__ float xs[64 * 152];
    __shared__ float vs[NF_ * 128];
    const int tid = threadIdx.x;
    const int b = blockIdx.x >> 4;
    const int t0 = (blockIdx.x & 15) << 7;
    const int tt = tid & 127;
    const int half_u = __builtin_amdgcn_readfirstlane(tid >> 7);
    const int g0 = half_u * 20;

    float acc[20];
#pragma unroll
    for (int j = 0; j < 20; ++j) acc[j] = 0.f;

    const float* w1p = w1c + g0 * 25;
    const float* tbp = tb2 + g0;

    for (int c0 = 0; c0 < C_; c0 += 64) {
        const int cc = (C_ - c0) < 64 ? (C_ - c0) : 64;
        __syncthreads();
        const int tot = cc * 152;
        for (int e = tid; e < tot; e += 256) {
            const int c = e / 152;
            const int i = e - c * 152;
            const int t = t0 - 12 + i;
            float v = 0.f;
            if ((unsigned)t < (unsigned)T_) v = x[(b * C_ + c0 + c) * T_ + t];
            xs[e] = v;
        }
        __syncthreads();
        for (int cl = 0; cl < cc; ++cl) {
            const int c = c0 + cl;
            // phase 1: tconv + BN + ELU for 40 filters x 128 t
            float xr[25];
#pragma unroll
            for (int kk = 0; kk < 25; ++kk) xr[kk] = xs[cl * 152 + tt + kk];
#pragma unroll
            for (int ff = 0; ff < 20; ++ff) {
                float a = tbp[ff];
#pragma unroll
                for (int kk = 0; kk < 25; ++kk)
                    a = fmaf(w1p[ff * 25 + kk], xr[kk], a);
                vs[(g0 + ff) * 128 + tt] = elu_f(a);
            }
            __syncthreads();
            // phase 2: accumulate sconv (weights via wave-uniform scalar loads)
            const float* w2p = w2u + (c * 2 + half_u) * 800;
#pragma unroll 2
            for (int f = 0; f < NF_; ++f) {
                const float v = vs[f * 128 + tt];
#pragma unroll
                for (int j = 0; j < 20; ++j)
                    acc[j] = fmaf(w2p[f * 20 + j], v, acc[j]);
            }
            __syncthreads();
        }
    }
    const int t = t0 + tt;
    if (t < T_) {
#pragma unroll
        for (int j = 0; j < 20; ++j) {
            float v = acc[j] + sb2[g0 + j];
            s2[(b * NF_ + g0 + j) * T_ + t] = elu_f(v);
        }
    }
}

// Fused: depthwise(15) + pointwise(80x40) + BN + ELU + pool4 + (proj∘wx0) -> xp[b][tp][k]
__global__ __launch_bounds__(256) void k2_dwpw(
    const float* __restrict__ s2, const float* __restrict__ dw_w,
    const float* __restrict__ dw_b, const float* __restrict__ pwc,
    const float* __restrict__ pb2, const float* __restrict__ WP,
    const float* __restrict__ bp, float* __restrict__ xp) {
    __shared__ float st[NF_ * 114];
    __shared__ float dwo[NF_ * 100];
    __shared__ float dwwl[NF_ * 15];
    __shared__ float dwbl[NF_];
    __shared__ float pwcl[80 * 40];
    __shared__ float pb2l[80];
    __shared__ float WPl[K_ * 80];
    __shared__ float bpl[K_];
    __shared__ float po[80 * 25];
    const int tid = threadIdx.x;
    const int b = blockIdx.x / 20;
    const int tp0 = (blockIdx.x % 20) * 25;
    const int tbase = tp0 * 4 - 7;
    for (int e = tid; e < NF_ * 114; e += 256) {
        const int f = e / 114;
        const int i = e - f * 114;
        const int t = tbase + i;
        st[e] = ((unsigned)t < (unsigned)T_) ? s2[(b * NF_ + f) * T_ + t] : 0.f;
    }
    for (int e = tid; e < 600; e += 256) dwwl[e] = dw_w[e];
    for (int e = tid; e < 3200; e += 256) pwcl[e] = pwc[e];
    for (int e = tid; e < 1280; e += 256) WPl[e] = WP[e];
    if (tid < NF_) dwbl[tid] = dw_b[tid];
    if (tid < 80) pb2l[tid] = pb2[tid];
    if (tid < K_) bpl[tid] = bp[tid];
    __syncthreads();
    for (int e = tid; e < 4000; e += 256) {
        const int f = e / 100;
        const int tq = e - f * 100;
        float a = dwbl[f];
#pragma unroll
        for (int kk = 0; kk < 15; ++kk)
            a = fmaf(dwwl[f * 15 + kk], st[f * 114 + tq + kk], a);
        dwo[e] = a;
    }
    __syncthreads();
    for (int e = tid; e < 2000; e += 256) {
        const int g = e / 25;
        const int tp = e - g * 25;
        float sum = 0.f;
#pragma unroll
        for (int dt = 0; dt < 4; ++dt) {
            float a = pb2l[g];
            for (int f = 0; f < NF_; ++f)
                a = fmaf(pwcl[g * 40 + f], dwo[f * 100 + tp * 4 + dt], a);
            sum += elu_f(a);
        }
        po[e] = sum * 0.25f;
    }
    __syncthreads();
    for (int e = tid; e < 400; e += 256) {
        const int tp = e >> 4;
        const int k = e & 15;
        float a = bpl[k];
        for (int g = 0; g < 80; ++g)
            a = fmaf(WPl[k * 80 + g], po[g * 25 + tp], a);
        xp[(b * TP_ + tp0 + tp) * K_ + k] = a;
    }
}

// Sequential 500-step scan. 4 blocks x 1 wave; each wave = 4 batches x 16 k.
__global__ __launch_bounds__(64) void k3_scan(
    const float* __restrict__ xp, const float* __restrict__ M0,
    const float* __restrict__ M1, const float* __restrict__ wx1,
    const float* __restrict__ b1, const float* __restrict__ ln0_g,
    const float* __restrict__ ln0_b, const float* __restrict__ ln1_g,
    const float* __restrict__ ln1_b, float* __restrict__ out) {
    const int lane = threadIdx.x;
    const int b = blockIdx.x * 4 + (lane >> 4);
    const int k = lane & 15;
    const int base = lane & 48;
    float M0r[16], M1r[16], w1r[16];
#pragma unroll
    for (int j = 0; j < 16; ++j) {
        M0r[j] = M0[k * 16 + j];
        M1r[j] = M1[k * 16 + j];
        w1r[j] = wx1[k * 16 + j];
    }
    const float b1r = b1[k];
    const float g0 = ln0_g[k], be0 = ln0_b[k];
    const float g1 = ln1_g[k], be1 = ln1_b[k];
    float h0 = 0.f, h1 = 0.f;
    const float* xpb = xp + b * TP_ * K_ + k;
    float xnext = xpb[0];
    for (int t = 0; t < TP_; ++t) {
        float pre = xnext;
        if (t + 1 < TP_) xnext = xpb[(t + 1) * K_];
#pragma unroll
        for (int j = 0; j < 16; ++j)
            pre = fmaf(__shfl(h0, base + j, 64), M0r[j], pre);
        float s1 = pre, s2 = pre * pre;
#pragma unroll
        for (int m = 1; m < 16; m <<= 1) {
            s1 += __shfl_xor(s1, m, 64);
            s2 += __shfl_xor(s2, m, 64);
        }
        float mu = s1 * 0.0625f;
        float var = s2 * 0.0625f - mu * mu;
        float r = rsqrtf(var + 1e-5f);
        h0 = tanh_f((pre - mu) * r * g0 + be0);
        float pre1 = b1r;
#pragma unroll
        for (int j = 0; j < 16; ++j) {
            pre1 = fmaf(__shfl(h0, base + j, 64), w1r[j], pre1);
            pre1 = fmaf(__shfl(h1, base + j, 64), M1r[j], pre1);
        }
        s1 = pre1; s2 = pre1 * pre1;
#pragma unroll
        for (int m = 1; m < 16; m <<= 1) {
            s1 += __shfl_xor(s1, m, 64);
            s2 += __shfl_xor(s2, m, 64);
        }
        mu = s1 * 0.0625f;
        var = s2 * 0.0625f - mu * mu;
        r = rsqrtf(var + 1e-5f);
        h1 = tanh_f((pre1 - mu) * r * g1 + be1);
    }
    out[b * K_ + k] = h1;               // Z
    if (k == 0) out[256 + b] = 1.0f;    // alpha = softmax over size-1 axis
}

extern "C" void kernel_launch(void* const* d_in, const int* in_sizes, int n_in,
                              void* d_out, int out_size, void* d_ws, size_t ws_size,
                              hipStream_t stream) {
    const float* x       = (const float*)d_in[0];
    const float* tconv_w = (const float*)d_in[1];
    const float* tconv_b = (const float*)d_in[2];
    const float* tbn_g   = (const float*)d_in[3];
    const float* tbn_b   = (const float*)d_in[4];
    const float* tbn_m   = (const float*)d_in[5];
    const float* tbn_v   = (const float*)d_in[6];
    const float* sconv_w = (const float*)d_in[7];
    const float* sconv_b = (const float*)d_in[8];
    const float* sbn_g   = (const float*)d_in[9];
    const float* sbn_b   = (const float*)d_in[10];
    const float* sbn_m   = (const float*)d_in[11];
    const float* sbn_v   = (const float*)d_in[12];
    const float* dw_w    = (const float*)d_in[13];
    const float* dw_b    = (const float*)d_in[14];
    const float* pw_w    = (const float*)d_in[15];
    const float* pw_b    = (const float*)d_in[16];
    const float* pbn_g   = (const float*)d_in[17];
    const float* pbn_b   = (const float*)d_in[18];
    const float* pbn_m   = (const float*)d_in[19];
    const float* pbn_v   = (const float*)d_in[20];
    const float* proj_w  = (const float*)d_in[21];
    const float* proj_b  = (const float*)d_in[22];
    const float* wx0     = (const float*)d_in[23];
    const float* L0      = (const float*)d_in[24];
    const float* ll0     = (const float*)d_in[25];
    const float* b0      = (const float*)d_in[26];
    const float* ln0_g   = (const float*)d_in[27];
    const float* ln0_b   = (const float*)d_in[28];
    const float* wx1     = (const float*)d_in[29];
    const float* L1      = (const float*)d_in[30];
    const float* ll1     = (const float*)d_in[31];
    const float* b1      = (const float*)d_in[32];
    const float* ln1_g   = (const float*)d_in[33];
    const float* ln1_b   = (const float*)d_in[34];
    float* ws = (float*)d_ws;
    float* out = (float*)d_out;

    P0 p;
    p.tconv_w = tconv_w; p.tconv_b = tconv_b;
    p.tbn_g = tbn_g; p.tbn_b = tbn_b; p.tbn_m = tbn_m; p.tbn_v = tbn_v;
    p.sconv_b = sconv_b; p.sbn_g = sbn_g; p.sbn_b = sbn_b; p.sbn_m = sbn_m; p.sbn_v = sbn_v;
    p.pw_w = pw_w; p.pw_b = pw_b;
    p.pbn_g = pbn_g; p.pbn_b = pbn_b; p.pbn_m = pbn_m; p.pbn_v = pbn_v;
    p.proj_w = proj_w; p.proj_b = proj_b; p.wx0 = wx0; p.b0 = b0;
    p.L0 = L0; p.ll0 = ll0; p.L1 = L1; p.ll1 = ll1;
    p.ws = ws;

    k0a_setup<<<dim3(1), dim3(256), 0, stream>>>(p);
    k0b_repack<<<dim3(256), dim3(256), 0, stream>>>(sconv_w, sbn_g, sbn_v, ws + OFF_W2U);
    k1_conv<<<dim3(256), dim3(256), 0, stream>>>(x, ws + OFF_W1C, ws + OFF_TB2,
                                                 ws + OFF_W2U, ws + OFF_SB2, ws + OFF_S2);
    k2_dwpw<<<dim3(320), dim3(256), 0, stream>>>(ws + OFF_S2, dw_w, dw_b, ws + OFF_PWC,
                                                 ws + OFF_PB2, ws + OFF_WP, ws + OFF_BP,
                                                 ws + OFF_XP);
    k3_scan<<<dim3(4), dim3(64), 0, stream>>>(ws + OFF_XP, ws + OFF_M0, ws + OFF_M1,
                                              wx1, b1, ln0_g, ln0_b, ln1_g, ln1_b, out);
}

// Round 2
// 992.598 us; speedup vs baseline: 1.7118x; 1.7118x over previous
//
#include <hip/hip_runtime.h>
#include <math.h>

#define B_ 16
#define C_ 129
#define T_ 2000
#define NF_ 40
#define ED_ 64
#define K_ 16
#define TP_ 500

#define CHUNK_C 22
#define NCHUNK 6

// workspace float offsets
#define OFF_W1C 0        // 1000   tconv weights * tbn scale
#define OFF_TB2 1000     // 40     folded tconv bias
#define OFF_SB2 1040     // 40     folded sconv bias
#define OFF_PWC 1088     // 3200   pw weights * pbn scale
#define OFF_PB2 4288     // 80     folded pw bias
#define OFF_WP  4368     // 1280   wx0 @ proj_w  (16x80)
#define OFF_BP  5648     // 16     wx0 @ proj_b + b0
#define OFF_M0  5664     // 256    L0@L0.T - exp(ll0) I
#define OFF_M1  5920     // 256    L1@L1.T - exp(ll1) I
#define OFF_W2U 8192     // 206400 repacked sconv weights [c][f][g] * sbn scale
#define OFF_S2  215040   // 1.28M  fused conv-stack output (post ELU)
#define OFF_XP  1495040  // 16*500*16  per-step cell0 input projection
#define OFF_S2R 1623040  // 1.28M  raw sconv accumulator (atomicAdd target)

__device__ __forceinline__ float elu_f(float x) {
    return x > 0.f ? x : (__expf(x) - 1.f);
}
__device__ __forceinline__ float tanh_f(float x) {
    float xc = fminf(fmaxf(x, -15.f), 15.f);
    float e2 = __expf(2.f * xc);
    return 1.f - 2.f / (e2 + 1.f);
}

struct P0 {
    const float *tconv_w, *tconv_b, *tbn_g, *tbn_b, *tbn_m, *tbn_v;
    const float *sconv_b, *sbn_g, *sbn_b, *sbn_m, *sbn_v;
    const float *pw_w, *pw_b, *pbn_g, *pbn_b, *pbn_m, *pbn_v;
    const float *proj_w, *proj_b, *wx0, *b0, *L0, *ll0, *L1, *ll1;
    float* ws;
};

__global__ __launch_bounds__(256) void k0a_setup(P0 p) {
    const int tid = threadIdx.x;
    float* ws = p.ws;
    const float eps = 1e-5f;
    for (int e = tid; e < 1000; e += 256) {
        const int f = e / 25;
        const float inv = p.tbn_g[f] / sqrtf(p.tbn_v[f] + eps);
        ws[OFF_W1C + e] = p.tconv_w[e] * inv;
    }
    for (int f = tid; f < NF_; f += 256) {
        const float inv = p.tbn_g[f] / sqrtf(p.tbn_v[f] + eps);
        ws[OFF_TB2 + f] = p.tconv_b[f] * inv + p.tbn_b[f] - p.tbn_m[f] * inv;
        const float sinv = p.sbn_g[f] / sqrtf(p.sbn_v[f] + eps);
        ws[OFF_SB2 + f] = p.sconv_b[f] * sinv + p.sbn_b[f] - p.sbn_m[f] * sinv;
    }
    for (int e = tid; e < 3200; e += 256) {
        const int g = e / 40;
        const float pinv = p.pbn_g[g] / sqrtf(p.pbn_v[g] + eps);
        ws[OFF_PWC + e] = p.pw_w[e] * pinv;
    }
    for (int g = tid; g < 80; g += 256) {
        const float pinv = p.pbn_g[g] / sqrtf(p.pbn_v[g] + eps);
        ws[OFF_PB2 + g] = p.pw_b[g] * pinv + p.pbn_b[g] - p.pbn_m[g] * pinv;
    }
    for (int e = tid; e < 1280; e += 256) {
        const int k = e / 80, g = e - k * 80;
        float a = 0.f;
        for (int ee = 0; ee < ED_; ++ee)
            a = fmaf(p.wx0[k * ED_ + ee], p.proj_w[ee * 80 + g], a);
        ws[OFF_WP + e] = a;
    }
    for (int k = tid; k < K_; k += 256) {
        float a = p.b0[k];
        for (int ee = 0; ee < ED_; ++ee)
            a = fmaf(p.wx0[k * ED_ + ee], p.proj_b[ee], a);
        ws[OFF_BP + k] = a;
    }
    for (int e = tid; e < 256; e += 256) {
        const int k = e >> 4, j = e & 15;
        float a0 = 0.f, a1 = 0.f;
        for (int i = 0; i < 16; ++i) {
            a0 = fmaf(p.L0[k * 16 + i], p.L0[j * 16 + i], a0);
            a1 = fmaf(p.L1[k * 16 + i], p.L1[j * 16 + i], a1);
        }
        if (k == j) { a0 -= expf(p.ll0[0]); a1 -= expf(p.ll1[0]); }
        ws[OFF_M0 + e] = a0;
        ws[OFF_M1 + e] = a1;
    }
}

// repack sconv_w[g][f][c] -> w2u[c][f][g], scaled by sbn inv (wave-uniform s_loads)
__global__ __launch_bounds__(256) void k0b_repack(
    const float* __restrict__ sconv_w, const float* __restrict__ sbn_g,
    const float* __restrict__ sbn_v, float* __restrict__ w2u) {
    const int total = C_ * 1600;
    for (int e = blockIdx.x * 256 + threadIdx.x; e < total; e += 256 * 256) {
        const int c = e / 1600;
        int r = e - c * 1600;
        const int f = r / 40;
        const int g = r - f * 40;
        const float sinv = sbn_g[g] / sqrtf(sbn_v[g] + 1e-5f);
        w2u[e] = sconv_w[g * (NF_ * C_) + f * C_ + c] * sinv;
    }
}

// zero the raw accumulator (ws is re-poisoned 0xAA before every launch)
__global__ __launch_bounds__(256) void k1z(float4* __restrict__ p) {
    const int i = blockIdx.x * 256 + threadIdx.x;
    if (i < 320000) p[i] = make_float4(0.f, 0.f, 0.f, 0.f);
}

// Fused tconv(25)+BN+ELU+sconv partial over a 22-channel chunk.
// grid = b(16) x ttile(8 x 256) x chunk(6) = 768 blocks, 1 barrier/block.
// Each thread owns one t, all 40 filters and all 40 output groups in regs.
__global__ __launch_bounds__(256) void k1_part(
    const float* __restrict__ x, const float* __restrict__ w1c,
    const float* __restrict__ tb2, const float* __restrict__ w2u,
    float* __restrict__ s2raw) {
    __shared__ float xs[CHUNK_C * 280];
    const int tid = threadIdx.x;
    const int chunk = blockIdx.x % NCHUNK;
    const int tmp = blockIdx.x / NCHUNK;
    const int tile = tmp & 7;
    const int b = tmp >> 3;
    const int c0 = chunk * CHUNK_C;
    const int cc = (C_ - c0) < CHUNK_C ? (C_ - c0) : CHUNK_C;
    const int t0 = tile << 8;

    const int tot = cc * 280;
    for (int e = tid; e < tot; e += 256) {
        const int cl = e / 280;
        const int i = e - cl * 280;
        const int t = t0 - 12 + i;
        float v = 0.f;
        if ((unsigned)t < (unsigned)T_) v = x[(b * C_ + c0 + cl) * T_ + t];
        xs[e] = v;
    }
    __syncthreads();

    float acc[NF_];
#pragma unroll
    for (int g = 0; g < NF_; ++g) acc[g] = 0.f;

    const int tt = tid;
    for (int cl = 0; cl < cc; ++cl) {
        float xr[25];
#pragma unroll
        for (int kk = 0; kk < 25; ++kk) xr[kk] = xs[cl * 280 + tt + kk];
        const float* w2p = w2u + (c0 + cl) * 1600;
#pragma unroll 2
        for (int f = 0; f < NF_; ++f) {
            const float* w1p = w1c + f * 25;
            float a0 = tb2[f], a1 = 0.f, a2 = 0.f, a3 = 0.f;
#pragma unroll
            for (int kk = 0; kk < 24; kk += 4) {
                a0 = fmaf(w1p[kk],     xr[kk],     a0);
                a1 = fmaf(w1p[kk + 1], xr[kk + 1], a1);
                a2 = fmaf(w1p[kk + 2], xr[kk + 2], a2);
                a3 = fmaf(w1p[kk + 3], xr[kk + 3], a3);
            }
            a0 = fmaf(w1p[24], xr[24], a0);
            const float e = elu_f((a0 + a1) + (a2 + a3));
#pragma unroll
            for (int g = 0; g < NF_; ++g)
                acc[g] = fmaf(w2p[f * 40 + g], e, acc[g]);
        }
    }
    const int t = t0 + tt;
    if (t < T_) {
#pragma unroll
        for (int g = 0; g < NF_; ++g)
            atomicAdd(&s2raw[(b * NF_ + g) * T_ + t], acc[g]);
    }
}

// s2 = elu(s2raw + sbias) , float4 over 1.28M elements
__global__ __launch_bounds__(256) void k1r(
    const float4* __restrict__ s2raw, const float* __restrict__ sb2,
    float4* __restrict__ s2) {
    const int i = blockIdx.x * 256 + threadIdx.x;
    if (i >= 320000) return;
    const int g = (i / 500) % NF_;
    const float bb = sb2[g];
    float4 v = s2raw[i];
    float4 o;
    o.x = elu_f(v.x + bb);
    o.y = elu_f(v.y + bb);
    o.z = elu_f(v.z + bb);
    o.w = elu_f(v.w + bb);
    s2[i] = o;
}

// Fused: depthwise(15) + pointwise(80x40) + BN + ELU + pool4 + (proj∘wx0) -> xp[b][tp][k]
__global__ __launch_bounds__(256) void k2_dwpw(
    const float* __restrict__ s2, const float* __restrict__ dw_w,
    const float* __restrict__ dw_b, const float* __restrict__ pwc,
    const float* __restrict__ pb2, const float* __restrict__ WP,
    const float* __restrict__ bp, float* __restrict__ xp) {
    __shared__ float st[NF_ * 114];
    __shared__ float dwo[NF_ * 100];
    __shared__ float dwwl[NF_ * 15];
    __shared__ float dwbl[NF_];
    __shared__ float pwcl[80 * 40];
    __shared__ float pb2l[80];
    __shared__ float WPl[K_ * 80];
    __shared__ float bpl[K_];
    __shared__ float po[80 * 25];
    const int tid = threadIdx.x;
    const int b = blockIdx.x / 20;
    const int tp0 = (blockIdx.x % 20) * 25;
    const int tbase = tp0 * 4 - 7;
    for (int e = tid; e < NF_ * 114; e += 256) {
        const int f = e / 114;
        const int i = e - f * 114;
        const int t = tbase + i;
        st[e] = ((unsigned)t < (unsigned)T_) ? s2[(b * NF_ + f) * T_ + t] : 0.f;
    }
    for (int e = tid; e < 600; e += 256) dwwl[e] = dw_w[e];
    for (int e = tid; e < 3200; e += 256) pwcl[e] = pwc[e];
    for (int e = tid; e < 1280; e += 256) WPl[e] = WP[e];
    if (tid < NF_) dwbl[tid] = dw_b[tid];
    if (tid < 80) pb2l[tid] = pb2[tid];
    if (tid < K_) bpl[tid] = bp[tid];
    __syncthreads();
    for (int e = tid; e < 4000; e += 256) {
        const int f = e / 100;
        const int tq = e - f * 100;
        float a = dwbl[f];
#pragma unroll
        for (int kk = 0; kk < 15; ++kk)
            a = fmaf(dwwl[f * 15 + kk], st[f * 114 + tq + kk], a);
        dwo[e] = a;
    }
    __syncthreads();
    for (int e = tid; e < 2000; e += 256) {
        const int g = e / 25;
        const int tp = e - g * 25;
        float sum = 0.f;
#pragma unroll
        for (int dt = 0; dt < 4; ++dt) {
            float a = pb2l[g];
            for (int f = 0; f < NF_; ++f)
                a = fmaf(pwcl[g * 40 + f], dwo[f * 100 + tp * 4 + dt], a);
            sum += elu_f(a);
        }
        po[e] = sum * 0.25f;
    }
    __syncthreads();
    for (int e = tid; e < 400; e += 256) {
        const int tp = e >> 4;
        const int k = e & 15;
        float a = bpl[k];
        for (int g = 0; g < 80; ++g)
            a = fmaf(WPl[k * 80 + g], po[g * 25 + tp], a);
        xp[(b * TP_ + tp0 + tp) * K_ + k] = a;
    }
}

// Sequential 500-step scan. 4 blocks x 1 wave; each wave = 4 batches x 16 k.
__global__ __launch_bounds__(64) void k3_scan(
    const float* __restrict__ xp, const float* __restrict__ M0,
    const float* __restrict__ M1, const float* __restrict__ wx1,
    const float* __restrict__ b1, const float* __restrict__ ln0_g,
    const float* __restrict__ ln0_b, const float* __restrict__ ln1_g,
    const float* __restrict__ ln1_b, float* __restrict__ out) {
    const int lane = threadIdx.x;
    const int b = blockIdx.x * 4 + (lane >> 4);
    const int k = lane & 15;
    const int base = lane & 48;
    float M0r[16], M1r[16], w1r[16];
#pragma unroll
    for (int j = 0; j < 16; ++j) {
        M0r[j] = M0[k * 16 + j];
        M1r[j] = M1[k * 16 + j];
        w1r[j] = wx1[k * 16 + j];
    }
    const float b1r = b1[k];
    const float g0 = ln0_g[k], be0 = ln0_b[k];
    const float g1 = ln1_g[k], be1 = ln1_b[k];
    float h0 = 0.f, h1 = 0.f;
    const float* xpb = xp + b * TP_ * K_ + k;
    float xnext = xpb[0];
    for (int t = 0; t < TP_; ++t) {
        float pre = xnext;
        if (t + 1 < TP_) xnext = xpb[(t + 1) * K_];
#pragma unroll
        for (int j = 0; j < 16; ++j)
            pre = fmaf(__shfl(h0, base + j, 64), M0r[j], pre);
        float s1 = pre, s2 = pre * pre;
#pragma unroll
        for (int m = 1; m < 16; m <<= 1) {
            s1 += __shfl_xor(s1, m, 64);
            s2 += __shfl_xor(s2, m, 64);
        }
        float mu = s1 * 0.0625f;
        float var = s2 * 0.0625f - mu * mu;
        float r = rsqrtf(var + 1e-5f);
        h0 = tanh_f((pre - mu) * r * g0 + be0);
        float pre1 = b1r;
#pragma unroll
        for (int j = 0; j < 16; ++j) {
            pre1 = fmaf(__shfl(h0, base + j, 64), w1r[j], pre1);
            pre1 = fmaf(__shfl(h1, base + j, 64), M1r[j], pre1);
        }
        s1 = pre1; s2 = pre1 * pre1;
#pragma unroll
        for (int m = 1; m < 16; m <<= 1) {
            s1 += __shfl_xor(s1, m, 64);
            s2 += __shfl_xor(s2, m, 64);
        }
        mu = s1 * 0.0625f;
        var = s2 * 0.0625f - mu * mu;
        r = rsqrtf(var + 1e-5f);
        h1 = tanh_f((pre1 - mu) * r * g1 + be1);
    }
    out[b * K_ + k] = h1;               // Z
    if (k == 0) out[256 + b] = 1.0f;    // alpha = softmax over size-1 axis
}

extern "C" void kernel_launch(void* const* d_in, const int* in_sizes, int n_in,
                              void* d_out, int out_size, void* d_ws, size_t ws_size,
                              hipStream_t stream) {
    const float* x       = (const float*)d_in[0];
    const float* tconv_w = (const float*)d_in[1];
    const float* tconv_b = (const float*)d_in[2];
    const float* tbn_g   = (const float*)d_in[3];
    const float* tbn_b   = (const float*)d_in[4];
    const float* tbn_m   = (const float*)d_in[5];
    const float* tbn_v   = (const float*)d_in[6];
    const float* sconv_w = (const float*)d_in[7];
    const float* sbn_g   = (const float*)d_in[9];
    const float* sbn_v   = (const float*)d_in[12];
    const float* dw_w    = (const float*)d_in[13];
    const float* dw_b    = (const float*)d_in[14];
    const float* wx1     = (const float*)d_in[29];
    const float* b1      = (const float*)d_in[32];
    const float* ln0_g   = (const float*)d_in[27];
    const float* ln0_b   = (const float*)d_in[28];
    const float* ln1_g   = (const float*)d_in[33];
    const float* ln1_b   = (const float*)d_in[34];
    float* ws = (float*)d_ws;
    float* out = (float*)d_out;

    P0 p;
    p.tconv_w = tconv_w; p.tconv_b = tconv_b;
    p.tbn_g = tbn_g; p.tbn_b = tbn_b; p.tbn_m = tbn_m; p.tbn_v = tbn_v;
    p.sconv_b = (const float*)d_in[8];
    p.sbn_g = sbn_g; p.sbn_b = (const float*)d_in[10];
    p.sbn_m = (const float*)d_in[11]; p.sbn_v = sbn_v;
    p.pw_w = (const float*)d_in[15]; p.pw_b = (const float*)d_in[16];
    p.pbn_g = (const float*)d_in[17]; p.pbn_b = (const float*)d_in[18];
    p.pbn_m = (const float*)d_in[19]; p.pbn_v = (const float*)d_in[20];
    p.proj_w = (const float*)d_in[21]; p.proj_b = (const float*)d_in[22];
    p.wx0 = (const float*)d_in[23]; p.b0 = (const float*)d_in[26];
    p.L0 = (const float*)d_in[24]; p.ll0 = (const float*)d_in[25];
    p.L1 = (const float*)d_in[30]; p.ll1 = (const float*)d_in[31];
    p.ws = ws;

    k0a_setup<<<dim3(1), dim3(256), 0, stream>>>(p);
    k0b_repack<<<dim3(256), dim3(256), 0, stream>>>(sconv_w, sbn_g, sbn_v, ws + OFF_W2U);
    k1z<<<dim3(1250), dim3(256), 0, stream>>>((float4*)(ws + OFF_S2R));
    k1_part<<<dim3(768), dim3(256), 0, stream>>>(x, ws + OFF_W1C, ws + OFF_TB2,
                                                 ws + OFF_W2U, ws + OFF_S2R);
    k1r<<<dim3(1250), dim3(256), 0, stream>>>((const float4*)(ws + OFF_S2R),
                                              ws + OFF_SB2, (float4*)(ws + OFF_S2));
    k2_dwpw<<<dim3(320), dim3(256), 0, stream>>>(ws + OFF_S2, dw_w, dw_b, ws + OFF_PWC,
                                                 ws + OFF_PB2, ws + OFF_WP, ws + OFF_BP,
                                                 ws + OFF_XP);
    k3_scan<<<dim3(4), dim3(64), 0, stream>>>(ws + OFF_XP, ws + OFF_M0, ws + OFF_M1,
                                              wx1, b1, ln0_g, ln0_b, ln1_g, ln1_b, out);
}

// Round 3
// 774.125 us; speedup vs baseline: 2.1949x; 1.2822x over previous
//
#include <hip/hip_runtime.h>
#include <math.h>

#define B_ 16
#define C_ 129
#define T_ 2000
#define NF_ 40
#define ED_ 64
#define K_ 16
#define TP_ 500

#define CHUNK_C 22
#define NCHUNK 6

// workspace float offsets
#define OFF_W1C 0        // 1000   tconv weights * tbn scale
#define OFF_TB2 1000     // 40     folded tconv bias
#define OFF_SB2 1040     // 40     folded sconv bias
#define OFF_PWC 1088     // 3200   pw weights * pbn scale
#define OFF_PB2 4288     // 80     folded pw bias
#define OFF_WP  4368     // 1280   wx0 @ proj_w  (16x80)
#define OFF_BP  5648     // 16     wx0 @ proj_b + b0
#define OFF_M0  5664     // 256    L0@L0.T - exp(ll0) I
#define OFF_M1  5920     // 256    L1@L1.T - exp(ll1) I
#define OFF_W2U 8192     // 206400 repacked sconv weights [c][f][g] * sbn scale
#define OFF_XP  1495040  // 16*500*16  per-step cell0 input projection
#define OFF_S2R 1623040  // 1.28M  raw sconv accumulator (atomicAdd target)

__device__ __forceinline__ float elu_f(float x) {
    return x > 0.f ? x : (__expf(x) - 1.f);
}
__device__ __forceinline__ float tanh_f(float x) {
    float xc = fminf(fmaxf(x, -15.f), 15.f);
    float e2 = __expf(2.f * xc);
    return 1.f - 2.f / (e2 + 1.f);
}

// DPP helpers: row_ror:n ctrl = 0x120+n, rows of 16 lanes (aligned with our
// 16-lane batch groups). Direction-proofed: the weight permutation is derived
// at init by running the SAME network on the lane index.
#define DPPF(v, ctrl) __int_as_float(__builtin_amdgcn_update_dpp( \
    0, __float_as_int(v), (ctrl), 0xF, 0xF, false))
#define DPPI(v, ctrl) __builtin_amdgcn_update_dpp(0, (v), (ctrl), 0xF, 0xF, false)

#define ALLGATHER16F(dst, src) do {        \
    dst[0] = (src);                        \
    dst[1] = DPPF(dst[0], 0x121);          \
    dst[2] = DPPF(dst[0], 0x122);          \
    dst[3] = DPPF(dst[1], 0x122);          \
    dst[4] = DPPF(dst[0], 0x124);          \
    dst[5] = DPPF(dst[1], 0x124);          \
    dst[6] = DPPF(dst[2], 0x124);          \
    dst[7] = DPPF(dst[3], 0x124);          \
    dst[8] = DPPF(dst[0], 0x128);          \
    dst[9] = DPPF(dst[1], 0x128);          \
    dst[10] = DPPF(dst[2], 0x128);         \
    dst[11] = DPPF(dst[3], 0x128);         \
    dst[12] = DPPF(dst[4], 0x128);         \
    dst[13] = DPPF(dst[5], 0x128);         \
    dst[14] = DPPF(dst[6], 0x128);         \
    dst[15] = DPPF(dst[7], 0x128);         \
} while (0)

#define ALLGATHER16I(dst, src) do {        \
    dst[0] = (src);                        \
    dst[1] = DPPI(dst[0], 0x121);          \
    dst[2] = DPPI(dst[0], 0x122);          \
    dst[3] = DPPI(dst[1], 0x122);          \
    dst[4] = DPPI(dst[0], 0x124);          \
    dst[5] = DPPI(dst[1], 0x124);          \
    dst[6] = DPPI(dst[2], 0x124);          \
    dst[7] = DPPI(dst[3], 0x124);          \
    dst[8] = DPPI(dst[0], 0x128);          \
    dst[9] = DPPI(dst[1], 0x128);          \
    dst[10] = DPPI(dst[2], 0x128);         \
    dst[11] = DPPI(dst[3], 0x128);         \
    dst[12] = DPPI(dst[4], 0x128);         \
    dst[13] = DPPI(dst[5], 0x128);         \
    dst[14] = DPPI(dst[6], 0x128);         \
    dst[15] = DPPI(dst[7], 0x128);         \
} while (0)

// full-sum over each 16-lane row via rotate-add (direction-agnostic)
#define RSUM16(s) do {                     \
    s += DPPF(s, 0x128);                   \
    s += DPPF(s, 0x124);                   \
    s += DPPF(s, 0x122);                   \
    s += DPPF(s, 0x121);                   \
} while (0)

struct P0 {
    const float *tconv_w, *tconv_b, *tbn_g, *tbn_b, *tbn_m, *tbn_v;
    const float *sconv_b, *sbn_g, *sbn_b, *sbn_m, *sbn_v;
    const float *pw_w, *pw_b, *pbn_g, *pbn_b, *pbn_m, *pbn_v;
    const float *proj_w, *proj_b, *wx0, *b0, *L0, *ll0, *L1, *ll1;
    float* ws;
};

__global__ __launch_bounds__(256) void k0a_setup(P0 p) {
    const int tid = threadIdx.x;
    float* ws = p.ws;
    const float eps = 1e-5f;
    for (int e = tid; e < 1000; e += 256) {
        const int f = e / 25;
        const float inv = p.tbn_g[f] / sqrtf(p.tbn_v[f] + eps);
        ws[OFF_W1C + e] = p.tconv_w[e] * inv;
    }
    for (int f = tid; f < NF_; f += 256) {
        const float inv = p.tbn_g[f] / sqrtf(p.tbn_v[f] + eps);
        ws[OFF_TB2 + f] = p.tconv_b[f] * inv + p.tbn_b[f] - p.tbn_m[f] * inv;
        const float sinv = p.sbn_g[f] / sqrtf(p.sbn_v[f] + eps);
        ws[OFF_SB2 + f] = p.sconv_b[f] * sinv + p.sbn_b[f] - p.sbn_m[f] * sinv;
    }
    for (int e = tid; e < 3200; e += 256) {
        const int g = e / 40;
        const float pinv = p.pbn_g[g] / sqrtf(p.pbn_v[g] + eps);
        ws[OFF_PWC + e] = p.pw_w[e] * pinv;
    }
    for (int g = tid; g < 80; g += 256) {
        const float pinv = p.pbn_g[g] / sqrtf(p.pbn_v[g] + eps);
        ws[OFF_PB2 + g] = p.pw_b[g] * pinv + p.pbn_b[g] - p.pbn_m[g] * pinv;
    }
    for (int e = tid; e < 1280; e += 256) {
        const int k = e / 80, g = e - k * 80;
        float a = 0.f;
        for (int ee = 0; ee < ED_; ++ee)
            a = fmaf(p.wx0[k * ED_ + ee], p.proj_w[ee * 80 + g], a);
        ws[OFF_WP + e] = a;
    }
    for (int k = tid; k < K_; k += 256) {
        float a = p.b0[k];
        for (int ee = 0; ee < ED_; ++ee)
            a = fmaf(p.wx0[k * ED_ + ee], p.proj_b[ee], a);
        ws[OFF_BP + k] = a;
    }
    for (int e = tid; e < 256; e += 256) {
        const int k = e >> 4, j = e & 15;
        float a0 = 0.f, a1 = 0.f;
        for (int i = 0; i < 16; ++i) {
            a0 = fmaf(p.L0[k * 16 + i], p.L0[j * 16 + i], a0);
            a1 = fmaf(p.L1[k * 16 + i], p.L1[j * 16 + i], a1);
        }
        if (k == j) { a0 -= expf(p.ll0[0]); a1 -= expf(p.ll1[0]); }
        ws[OFF_M0 + e] = a0;
        ws[OFF_M1 + e] = a1;
    }
}

// repack sconv_w[g][f][c] -> w2u[c][f][g], scaled by sbn inv (wave-uniform s_loads)
__global__ __launch_bounds__(256) void k0b_repack(
    const float* __restrict__ sconv_w, const float* __restrict__ sbn_g,
    const float* __restrict__ sbn_v, float* __restrict__ w2u) {
    const int total = C_ * 1600;
    for (int e = blockIdx.x * 256 + threadIdx.x; e < total; e += 256 * 256) {
        const int c = e / 1600;
        int r = e - c * 1600;
        const int f = r / 40;
        const int g = r - f * 40;
        const float sinv = sbn_g[g] / sqrtf(sbn_v[g] + 1e-5f);
        w2u[e] = sconv_w[g * (NF_ * C_) + f * C_ + c] * sinv;
    }
}

// zero the raw accumulator (ws is re-poisoned 0xAA before every launch)
__global__ __launch_bounds__(256) void k1z(float4* __restrict__ p) {
    const int i = blockIdx.x * 256 + threadIdx.x;
    if (i < 320000) p[i] = make_float4(0.f, 0.f, 0.f, 0.f);
}

// Fused tconv(25)+BN+ELU+sconv partial over a 22-channel chunk.
// grid = b(16) x ttile(8 x 256) x chunk(6) = 768 blocks, 1 barrier/block.
__global__ __launch_bounds__(256) void k1_part(
    const float* __restrict__ x, const float* __restrict__ w1c,
    const float* __restrict__ tb2, const float* __restrict__ w2u,
    float* __restrict__ s2raw) {
    __shared__ float xs[CHUNK_C * 280];
    const int tid = threadIdx.x;
    const int chunk = blockIdx.x % NCHUNK;
    const int tmp = blockIdx.x / NCHUNK;
    const int tile = tmp & 7;
    const int b = tmp >> 3;
    const int c0 = chunk * CHUNK_C;
    const int cc = (C_ - c0) < CHUNK_C ? (C_ - c0) : CHUNK_C;
    const int t0 = tile << 8;

    const int tot = cc * 280;
    for (int e = tid; e < tot; e += 256) {
        const int cl = e / 280;
        const int i = e - cl * 280;
        const int t = t0 - 12 + i;
        float v = 0.f;
        if ((unsigned)t < (unsigned)T_) v = x[(b * C_ + c0 + cl) * T_ + t];
        xs[e] = v;
    }
    __syncthreads();

    float acc[NF_];
#pragma unroll
    for (int g = 0; g < NF_; ++g) acc[g] = 0.f;

    const int tt = tid;
    for (int cl = 0; cl < cc; ++cl) {
        float xr[25];
#pragma unroll
        for (int kk = 0; kk < 25; ++kk) xr[kk] = xs[cl * 280 + tt + kk];
        const float* w2p = w2u + (c0 + cl) * 1600;
#pragma unroll 2
        for (int f = 0; f < NF_; ++f) {
            const float* w1p = w1c + f * 25;
            float a0 = tb2[f], a1 = 0.f, a2 = 0.f, a3 = 0.f;
#pragma unroll
            for (int kk = 0; kk < 24; kk += 4) {
                a0 = fmaf(w1p[kk],     xr[kk],     a0);
                a1 = fmaf(w1p[kk + 1], xr[kk + 1], a1);
                a2 = fmaf(w1p[kk + 2], xr[kk + 2], a2);
                a3 = fmaf(w1p[kk + 3], xr[kk + 3], a3);
            }
            a0 = fmaf(w1p[24], xr[24], a0);
            const float e = elu_f((a0 + a1) + (a2 + a3));
#pragma unroll
            for (int g = 0; g < NF_; ++g)
                acc[g] = fmaf(w2p[f * 40 + g], e, acc[g]);
        }
    }
    const int t = t0 + tt;
    if (t < T_) {
#pragma unroll
        for (int g = 0; g < NF_; ++g)
            atomicAdd(&s2raw[(b * NF_ + g) * T_ + t], acc[g]);
    }
}

// Fused: bias+ELU on s2raw at stage time, depthwise(15) + pointwise(80x40)
// + BN + ELU + pool4 + (proj∘wx0) -> xp[b][tp][k]
__global__ __launch_bounds__(256) void k2_dwpw(
    const float* __restrict__ s2raw, const float* __restrict__ sb2,
    const float* __restrict__ dw_w, const float* __restrict__ dw_b,
    const float* __restrict__ pwc, const float* __restrict__ pb2,
    const float* __restrict__ WP, const float* __restrict__ bp,
    float* __restrict__ xp) {
    __shared__ float st[NF_ * 114];
    __shared__ float dwo[NF_ * 100];
    __shared__ float dwwl[NF_ * 15];
    __shared__ float dwbl[NF_];
    __shared__ float pwcl[80 * 40];
    __shared__ float pb2l[80];
    __shared__ float WPl[K_ * 80];
    __shared__ float bpl[K_];
    __shared__ float po[80 * 25];
    const int tid = threadIdx.x;
    const int b = blockIdx.x / 20;
    const int tp0 = (blockIdx.x % 20) * 25;
    const int tbase = tp0 * 4 - 7;
    for (int e = tid; e < NF_ * 114; e += 256) {
        const int f = e / 114;
        const int i = e - f * 114;
        const int t = tbase + i;
        float v = 0.f;
        if ((unsigned)t < (unsigned)T_)
            v = elu_f(s2raw[(b * NF_ + f) * T_ + t] + sb2[f]);
        st[e] = v;
    }
    for (int e = tid; e < 600; e += 256) dwwl[e] = dw_w[e];
    for (int e = tid; e < 3200; e += 256) pwcl[e] = pwc[e];
    for (int e = tid; e < 1280; e += 256) WPl[e] = WP[e];
    if (tid < NF_) dwbl[tid] = dw_b[tid];
    if (tid < 80) pb2l[tid] = pb2[tid];
    if (tid < K_) bpl[tid] = bp[tid];
    __syncthreads();
    for (int e = tid; e < 4000; e += 256) {
        const int f = e / 100;
        const int tq = e - f * 100;
        float a = dwbl[f];
#pragma unroll
        for (int kk = 0; kk < 15; ++kk)
            a = fmaf(dwwl[f * 15 + kk], st[f * 114 + tq + kk], a);
        dwo[e] = a;
    }
    __syncthreads();
    for (int e = tid; e < 2000; e += 256) {
        const int g = e / 25;
        const int tp = e - g * 25;
        float sum = 0.f;
#pragma unroll
        for (int dt = 0; dt < 4; ++dt) {
            float a = pb2l[g];
            for (int f = 0; f < NF_; ++f)
                a = fmaf(pwcl[g * 40 + f], dwo[f * 100 + tp * 4 + dt], a);
            sum += elu_f(a);
        }
        po[e] = sum * 0.25f;
    }
    __syncthreads();
    for (int e = tid; e < 400; e += 256) {
        const int tp = e >> 4;
        const int k = e & 15;
        float a = bpl[k];
        for (int g = 0; g < 80; ++g)
            a = fmaf(WPl[k * 80 + g], po[g * 25 + tp], a);
        xp[(b * TP_ + tp0 + tp) * K_ + k] = a;
    }
}

// Sequential 500-step scan, DPP-only cross-lane. 4 blocks x 1 wave;
// each wave = 4 batches x 16 k (16-lane groups == DPP rows).
__global__ __launch_bounds__(64, 1) void k3_scan(
    const float* __restrict__ xp, const float* __restrict__ M0,
    const float* __restrict__ M1, const float* __restrict__ wx1,
    const float* __restrict__ b1, const float* __restrict__ ln0_g,
    const float* __restrict__ ln0_b, const float* __restrict__ ln1_g,
    const float* __restrict__ ln1_b, float* __restrict__ out) {
    const int lane = threadIdx.x;
    const int b = blockIdx.x * 4 + (lane >> 4);
    const int k = lane & 15;

    // run the gather network on the lane index -> per-lane permutation,
    // then permute the weight rows to match (direction-proof).
    int pidx[16];
    ALLGATHER16I(pidx, k);

    float M0r[16], M1r[16], w1r[16];
#pragma unroll
    for (int j = 0; j < 16; ++j) {
        M0r[j] = M0[k * 16 + pidx[j]];
        M1r[j] = M1[k * 16 + pidx[j]];
        w1r[j] = wx1[k * 16 + pidx[j]];
    }
    const float b1r = b1[k];
    const float g0 = ln0_g[k], be0 = ln0_b[k];
    const float g1 = ln1_g[k], be1 = ln1_b[k];
    float h0 = 0.f, h1 = 0.f;
    const float* xpb = xp + b * TP_ * K_ + k;
    float xn0 = xpb[0];
    float xn1 = xpb[K_];
    for (int t = 0; t < TP_; ++t) {
        float h0g[16], h1g[16];
        ALLGATHER16F(h0g, h0);
        ALLGATHER16F(h1g, h1);
        float p0 = xn0, p1 = 0.f, p2 = 0.f, p3 = 0.f;
        xn0 = xn1;
        if (t + 2 < TP_) xn1 = xpb[(t + 2) * K_];
#pragma unroll
        for (int j = 0; j < 16; j += 4) {
            p0 = fmaf(M0r[j],     h0g[j],     p0);
            p1 = fmaf(M0r[j + 1], h0g[j + 1], p1);
            p2 = fmaf(M0r[j + 2], h0g[j + 2], p2);
            p3 = fmaf(M0r[j + 3], h0g[j + 3], p3);
        }
        const float pre = (p0 + p1) + (p2 + p3);
        float s1 = pre, s2 = pre * pre;
        RSUM16(s1);
        RSUM16(s2);
        float mu = s1 * 0.0625f;
        float var = s2 * 0.0625f - mu * mu;
        float r = rsqrtf(var + 1e-5f);
        h0 = tanh_f((pre - mu) * r * g0 + be0);

        float h0n[16];
        ALLGATHER16F(h0n, h0);
        float q0 = b1r, q1 = 0.f, q2 = 0.f, q3 = 0.f;
#pragma unroll
        for (int j = 0; j < 16; j += 4) {
            q0 = fmaf(w1r[j],     h0n[j],     q0);
            q1 = fmaf(w1r[j + 1], h0n[j + 1], q1);
            q2 = fmaf(w1r[j + 2], h0n[j + 2], q2);
            q3 = fmaf(w1r[j + 3], h0n[j + 3], q3);
        }
#pragma unroll
        for (int j = 0; j < 16; j += 4) {
            q0 = fmaf(M1r[j],     h1g[j],     q0);
            q1 = fmaf(M1r[j + 1], h1g[j + 1], q1);
            q2 = fmaf(M1r[j + 2], h1g[j + 2], q2);
            q3 = fmaf(M1r[j + 3], h1g[j + 3], q3);
        }
        const float pre1 = (q0 + q1) + (q2 + q3);
        s1 = pre1; s2 = pre1 * pre1;
        RSUM16(s1);
        RSUM16(s2);
        mu = s1 * 0.0625f;
        var = s2 * 0.0625f - mu * mu;
        r = rsqrtf(var + 1e-5f);
        h1 = tanh_f((pre1 - mu) * r * g1 + be1);
    }
    out[b * K_ + k] = h1;               // Z
    if (k == 0) out[256 + b] = 1.0f;    // alpha = softmax over size-1 axis
}

extern "C" void kernel_launch(void* const* d_in, const int* in_sizes, int n_in,
                              void* d_out, int out_size, void* d_ws, size_t ws_size,
                              hipStream_t stream) {
    const float* x       = (const float*)d_in[0];
    const float* sconv_w = (const float*)d_in[7];
    const float* sbn_g   = (const float*)d_in[9];
    const float* sbn_v   = (const float*)d_in[12];
    const float* dw_w    = (const float*)d_in[13];
    const float* dw_b    = (const float*)d_in[14];
    const float* wx1     = (const float*)d_in[29];
    const float* b1      = (const float*)d_in[32];
    const float* ln0_g   = (const float*)d_in[27];
    const float* ln0_b   = (const float*)d_in[28];
    const float* ln1_g   = (const float*)d_in[33];
    const float* ln1_b   = (const float*)d_in[34];
    float* ws = (float*)d_ws;
    float* out = (float*)d_out;

    P0 p;
    p.tconv_w = (const float*)d_in[1]; p.tconv_b = (const float*)d_in[2];
    p.tbn_g = (const float*)d_in[3]; p.tbn_b = (const float*)d_in[4];
    p.tbn_m = (const float*)d_in[5]; p.tbn_v = (const float*)d_in[6];
    p.sconv_b = (const float*)d_in[8];
    p.sbn_g = sbn_g; p.sbn_b = (const float*)d_in[10];
    p.sbn_m = (const float*)d_in[11]; p.sbn_v = sbn_v;
    p.pw_w = (const float*)d_in[15]; p.pw_b = (const float*)d_in[16];
    p.pbn_g = (const float*)d_in[17]; p.pbn_b = (const float*)d_in[18];
    p.pbn_m = (const float*)d_in[19]; p.pbn_v = (const float*)d_in[20];
    p.proj_w = (const float*)d_in[21]; p.proj_b = (const float*)d_in[22];
    p.wx0 = (const float*)d_in[23]; p.b0 = (const float*)d_in[26];
    p.L0 = (const float*)d_in[24]; p.ll0 = (const float*)d_in[25];
    p.L1 = (const float*)d_in[30]; p.ll1 = (const float*)d_in[31];
    p.ws = ws;

    k0a_setup<<<dim3(1), dim3(256), 0, stream>>>(p);
    k0b_repack<<<dim3(256), dim3(256), 0, stream>>>(sconv_w, sbn_g, sbn_v, ws + OFF_W2U);
    k1z<<<dim3(1250), dim3(256), 0, stream>>>((float4*)(ws + OFF_S2R));
    k1_part<<<dim3(768), dim3(256), 0, stream>>>(x, ws + OFF_W1C, ws + OFF_TB2,
                                                 ws + OFF_W2U, ws + OFF_S2R);
    k2_dwpw<<<dim3(320), dim3(256), 0, stream>>>(ws + OFF_S2R, ws + OFF_SB2,
                                                 dw_w, dw_b, ws + OFF_PWC,
                                                 ws + OFF_PB2, ws + OFF_WP, ws + OFF_BP,
                                                 ws + OFF_XP);
    k3_scan<<<dim3(4), dim3(64), 0, stream>>>(ws + OFF_XP, ws + OFF_M0, ws + OFF_M1,
                                              wx1, b1, ln0_g, ln0_b, ln1_g, ln1_b, out);
}

// Round 4
// 683.675 us; speedup vs baseline: 2.4853x; 1.1323x over previous
//
#include <hip/hip_runtime.h>
#include <math.h>

#define B_ 16
#define C_ 129
#define T_ 2000
#define NF_ 40
#define ED_ 64
#define K_ 16
#define TP_ 500

#define CHUNK_C 11
#define NCHUNK 12

// workspace float offsets
#define OFF_W1C 0        // 1000   tconv weights * tbn scale
#define OFF_TB2 1000     // 40     folded tconv bias
#define OFF_SB2 1040     // 40     folded sconv bias
#define OFF_PWC 1088     // 3200   pw weights * pbn scale
#define OFF_PB2 4288     // 80     folded pw bias
#define OFF_WP  4368     // 1280   wx0 @ proj_w  (16x80)
#define OFF_BP  5648     // 16     wx0 @ proj_b + b0
#define OFF_M0  5664     // 256    L0@L0.T - exp(ll0) I
#define OFF_M1  5920     // 256    L1@L1.T - exp(ll1) I
#define OFF_W2U 8192     // 206400 repacked sconv weights [c][f][g] * sbn scale
#define OFF_XP  1495040  // 16*500*16  per-step cell0 input projection
#define OFF_S2R 1623040  // 1.28M  raw sconv accumulator (atomicAdd target)

__device__ __forceinline__ float elu_f(float x) {
    return x > 0.f ? x : (__expf(x) - 1.f);
}
__device__ __forceinline__ float tanh_f(float x) {
    float xc = fminf(fmaxf(x, -15.f), 15.f);
    float e2 = __expf(2.f * xc);
    return 1.f - 2.f / (e2 + 1.f);
}

// DPP helpers: row_ror:n ctrl = 0x120+n, rows of 16 lanes (aligned with our
// 16-lane batch groups). Direction-proofed: the weight permutation is derived
// at init by running the SAME network on the lane index.
#define DPPF(v, ctrl) __int_as_float(__builtin_amdgcn_update_dpp( \
    0, __float_as_int(v), (ctrl), 0xF, 0xF, false))
#define DPPI(v, ctrl) __builtin_amdgcn_update_dpp(0, (v), (ctrl), 0xF, 0xF, false)

#define ALLGATHER16F(dst, src) do {        \
    dst[0] = (src);                        \
    dst[1] = DPPF(dst[0], 0x121);          \
    dst[2] = DPPF(dst[0], 0x122);          \
    dst[3] = DPPF(dst[1], 0x122);          \
    dst[4] = DPPF(dst[0], 0x124);          \
    dst[5] = DPPF(dst[1], 0x124);          \
    dst[6] = DPPF(dst[2], 0x124);          \
    dst[7] = DPPF(dst[3], 0x124);          \
    dst[8] = DPPF(dst[0], 0x128);          \
    dst[9] = DPPF(dst[1], 0x128);          \
    dst[10] = DPPF(dst[2], 0x128);         \
    dst[11] = DPPF(dst[3], 0x128);         \
    dst[12] = DPPF(dst[4], 0x128);         \
    dst[13] = DPPF(dst[5], 0x128);         \
    dst[14] = DPPF(dst[6], 0x128);         \
    dst[15] = DPPF(dst[7], 0x128);         \
} while (0)

#define ALLGATHER16I(dst, src) do {        \
    dst[0] = (src);                        \
    dst[1] = DPPI(dst[0], 0x121);          \
    dst[2] = DPPI(dst[0], 0x122);          \
    dst[3] = DPPI(dst[1], 0x122);          \
    dst[4] = DPPI(dst[0], 0x124);          \
    dst[5] = DPPI(dst[1], 0x124);          \
    dst[6] = DPPI(dst[2], 0x124);          \
    dst[7] = DPPI(dst[3], 0x124);          \
    dst[8] = DPPI(dst[0], 0x128);          \
    dst[9] = DPPI(dst[1], 0x128);          \
    dst[10] = DPPI(dst[2], 0x128);         \
    dst[11] = DPPI(dst[3], 0x128);         \
    dst[12] = DPPI(dst[4], 0x128);         \
    dst[13] = DPPI(dst[5], 0x128);         \
    dst[14] = DPPI(dst[6], 0x128);         \
    dst[15] = DPPI(dst[7], 0x128);         \
} while (0)

// full-sum over each 16-lane row via rotate-add (direction-agnostic)
#define RSUM16(s) do {                     \
    s += DPPF(s, 0x128);                   \
    s += DPPF(s, 0x124);                   \
    s += DPPF(s, 0x122);                   \
    s += DPPF(s, 0x121);                   \
} while (0)

struct P0 {
    const float *tconv_w, *tconv_b, *tbn_g, *tbn_b, *tbn_m, *tbn_v;
    const float *sconv_b, *sbn_g, *sbn_b, *sbn_m, *sbn_v;
    const float *pw_w, *pw_b, *pbn_g, *pbn_b, *pbn_m, *pbn_v;
    const float *proj_w, *proj_b, *wx0, *b0, *L0, *ll0, *L1, *ll1;
    float* ws;
};

__global__ __launch_bounds__(256) void k0a_setup(P0 p) {
    const int tid = blockIdx.x * 256 + threadIdx.x;
    const int stride = gridDim.x * 256;
    float* ws = p.ws;
    const float eps = 1e-5f;
    for (int e = tid; e < 1000; e += stride) {
        const int f = e / 25;
        const float inv = p.tbn_g[f] / sqrtf(p.tbn_v[f] + eps);
        ws[OFF_W1C + e] = p.tconv_w[e] * inv;
    }
    for (int f = tid; f < NF_; f += stride) {
        const float inv = p.tbn_g[f] / sqrtf(p.tbn_v[f] + eps);
        ws[OFF_TB2 + f] = p.tconv_b[f] * inv + p.tbn_b[f] - p.tbn_m[f] * inv;
        const float sinv = p.sbn_g[f] / sqrtf(p.sbn_v[f] + eps);
        ws[OFF_SB2 + f] = p.sconv_b[f] * sinv + p.sbn_b[f] - p.sbn_m[f] * sinv;
    }
    for (int e = tid; e < 3200; e += stride) {
        const int g = e / 40;
        const float pinv = p.pbn_g[g] / sqrtf(p.pbn_v[g] + eps);
        ws[OFF_PWC + e] = p.pw_w[e] * pinv;
    }
    for (int g = tid; g < 80; g += stride) {
        const float pinv = p.pbn_g[g] / sqrtf(p.pbn_v[g] + eps);
        ws[OFF_PB2 + g] = p.pw_b[g] * pinv + p.pbn_b[g] - p.pbn_m[g] * pinv;
    }
    for (int e = tid; e < 1280; e += stride) {
        const int k = e / 80, g = e - k * 80;
        float a = 0.f;
        for (int ee = 0; ee < ED_; ++ee)
            a = fmaf(p.wx0[k * ED_ + ee], p.proj_w[ee * 80 + g], a);
        ws[OFF_WP + e] = a;
    }
    for (int k = tid; k < K_; k += stride) {
        float a = p.b0[k];
        for (int ee = 0; ee < ED_; ++ee)
            a = fmaf(p.wx0[k * ED_ + ee], p.proj_b[ee], a);
        ws[OFF_BP + k] = a;
    }
    for (int e = tid; e < 256; e += stride) {
        const int k = e >> 4, j = e & 15;
        float a0 = 0.f, a1 = 0.f;
        for (int i = 0; i < 16; ++i) {
            a0 = fmaf(p.L0[k * 16 + i], p.L0[j * 16 + i], a0);
            a1 = fmaf(p.L1[k * 16 + i], p.L1[j * 16 + i], a1);
        }
        if (k == j) { a0 -= expf(p.ll0[0]); a1 -= expf(p.ll1[0]); }
        ws[OFF_M0 + e] = a0;
        ws[OFF_M1 + e] = a1;
    }
}

// repack sconv_w[g][f][c] -> w2u[c][f][g], scaled by sbn inv (wave-uniform s_loads)
__global__ __launch_bounds__(256) void k0b_repack(
    const float* __restrict__ sconv_w, const float* __restrict__ sbn_g,
    const float* __restrict__ sbn_v, float* __restrict__ w2u) {
    const int total = C_ * 1600;
    for (int e = blockIdx.x * 256 + threadIdx.x; e < total; e += 256 * 256) {
        const int c = e / 1600;
        int r = e - c * 1600;
        const int f = r / 40;
        const int g = r - f * 40;
        const float sinv = sbn_g[g] / sqrtf(sbn_v[g] + 1e-5f);
        w2u[e] = sconv_w[g * (NF_ * C_) + f * C_ + c] * sinv;
    }
}

// zero the raw accumulator (ws is re-poisoned 0xAA before every launch)
__global__ __launch_bounds__(256) void k1z(float4* __restrict__ p) {
    const int i = blockIdx.x * 256 + threadIdx.x;
    if (i < 320000) p[i] = make_float4(0.f, 0.f, 0.f, 0.f);
}

// Fused tconv(25)+BN+ELU+sconv partial over an 11-channel chunk.
// grid = b(16) x ttile(8 x 256) x chunk(12) = 1536 blocks -> 6 blocks/CU,
// 24 waves/CU (occupancy was the round-3 limiter at 768 blocks).
__global__ __launch_bounds__(256) void k1_part(
    const float* __restrict__ x, const float* __restrict__ w1c,
    const float* __restrict__ tb2, const float* __restrict__ w2u,
    float* __restrict__ s2raw) {
    __shared__ float xs[CHUNK_C * 280];
    const int tid = threadIdx.x;
    const int chunk = blockIdx.x % NCHUNK;
    const int tmp = blockIdx.x / NCHUNK;
    const int tile = tmp & 7;
    const int b = tmp >> 3;
    const int c0 = chunk * CHUNK_C;
    const int cc = (C_ - c0) < CHUNK_C ? (C_ - c0) : CHUNK_C;
    const int t0 = tile << 8;

    const int tot = cc * 280;
    for (int e = tid; e < tot; e += 256) {
        const int cl = e / 280;
        const int i = e - cl * 280;
        const int t = t0 - 12 + i;
        float v = 0.f;
        if ((unsigned)t < (unsigned)T_) v = x[(b * C_ + c0 + cl) * T_ + t];
        xs[e] = v;
    }
    __syncthreads();

    float acc[NF_];
#pragma unroll
    for (int g = 0; g < NF_; ++g) acc[g] = 0.f;

    const int tt = tid;
    for (int cl = 0; cl < cc; ++cl) {
        float xr[25];
#pragma unroll
        for (int kk = 0; kk < 25; ++kk) xr[kk] = xs[cl * 280 + tt + kk];
        const float* w2p = w2u + (c0 + cl) * 1600;
#pragma unroll 2
        for (int f = 0; f < NF_; ++f) {
            const float* w1p = w1c + f * 25;
            float a0 = tb2[f], a1 = 0.f, a2 = 0.f, a3 = 0.f;
#pragma unroll
            for (int kk = 0; kk < 24; kk += 4) {
                a0 = fmaf(w1p[kk],     xr[kk],     a0);
                a1 = fmaf(w1p[kk + 1], xr[kk + 1], a1);
                a2 = fmaf(w1p[kk + 2], xr[kk + 2], a2);
                a3 = fmaf(w1p[kk + 3], xr[kk + 3], a3);
            }
            a0 = fmaf(w1p[24], xr[24], a0);
            const float e = elu_f((a0 + a1) + (a2 + a3));
#pragma unroll
            for (int g = 0; g < NF_; ++g)
                acc[g] = fmaf(w2p[f * 40 + g], e, acc[g]);
        }
    }
    const int t = t0 + tt;
    if (t < T_) {
#pragma unroll
        for (int g = 0; g < NF_; ++g)
            atomicAdd(&s2raw[(b * NF_ + g) * T_ + t], acc[g]);
    }
}

// Fused: bias+ELU on s2raw at stage time, depthwise(15) + pointwise(80x40)
// + BN + ELU + pool4 + (proj∘wx0) -> xp[b][tp][k]
__global__ __launch_bounds__(256) void k2_dwpw(
    const float* __restrict__ s2raw, const float* __restrict__ sb2,
    const float* __restrict__ dw_w, const float* __restrict__ dw_b,
    const float* __restrict__ pwc, const float* __restrict__ pb2,
    const float* __restrict__ WP, const float* __restrict__ bp,
    float* __restrict__ xp) {
    __shared__ float st[NF_ * 114];
    __shared__ float dwo[NF_ * 100];
    __shared__ float dwwl[NF_ * 15];
    __shared__ float dwbl[NF_];
    __shared__ float pwcl[80 * 40];
    __shared__ float pb2l[80];
    __shared__ float WPl[K_ * 80];
    __shared__ float bpl[K_];
    __shared__ float po[80 * 25];
    const int tid = threadIdx.x;
    const int b = blockIdx.x / 20;
    const int tp0 = (blockIdx.x % 20) * 25;
    const int tbase = tp0 * 4 - 7;
    for (int e = tid; e < NF_ * 114; e += 256) {
        const int f = e / 114;
        const int i = e - f * 114;
        const int t = tbase + i;
        float v = 0.f;
        if ((unsigned)t < (unsigned)T_)
            v = elu_f(s2raw[(b * NF_ + f) * T_ + t] + sb2[f]);
        st[e] = v;
    }
    for (int e = tid; e < 600; e += 256) dwwl[e] = dw_w[e];
    for (int e = tid; e < 3200; e += 256) pwcl[e] = pwc[e];
    for (int e = tid; e < 1280; e += 256) WPl[e] = WP[e];
    if (tid < NF_) dwbl[tid] = dw_b[tid];
    if (tid < 80) pb2l[tid] = pb2[tid];
    if (tid < K_) bpl[tid] = bp[tid];
    __syncthreads();
    for (int e = tid; e < 4000; e += 256) {
        const int f = e / 100;
        const int tq = e - f * 100;
        float a = dwbl[f];
#pragma unroll
        for (int kk = 0; kk < 15; ++kk)
            a = fmaf(dwwl[f * 15 + kk], st[f * 114 + tq + kk], a);
        dwo[e] = a;
    }
    __syncthreads();
    for (int e = tid; e < 2000; e += 256) {
        const int g = e / 25;
        const int tp = e - g * 25;
        float sum = 0.f;
#pragma unroll
        for (int dt = 0; dt < 4; ++dt) {
            float a = pb2l[g];
            for (int f = 0; f < NF_; ++f)
                a = fmaf(pwcl[g * 40 + f], dwo[f * 100 + tp * 4 + dt], a);
            sum += elu_f(a);
        }
        po[e] = sum * 0.25f;
    }
    __syncthreads();
    for (int e = tid; e < 400; e += 256) {
        const int tp = e >> 4;
        const int k = e & 15;
        float a = bpl[k];
        for (int g = 0; g < 80; ++g)
            a = fmaf(WPl[k * 80 + g], po[g * 25 + tp], a);
        xp[(b * TP_ + tp0 + tp) * K_ + k] = a;
    }
}

// Sequential 500-step scan, DPP-only cross-lane. 4 blocks x 1 wave;
// each wave = 4 batches x 16 k (16-lane groups == DPP rows).
__global__ __launch_bounds__(64, 1) void k3_scan(
    const float* __restrict__ xp, const float* __restrict__ M0,
    const float* __restrict__ M1, const float* __restrict__ wx1,
    const float* __restrict__ b1, const float* __restrict__ ln0_g,
    const float* __restrict__ ln0_b, const float* __restrict__ ln1_g,
    const float* __restrict__ ln1_b, float* __restrict__ out) {
    const int lane = threadIdx.x;
    const int b = blockIdx.x * 4 + (lane >> 4);
    const int k = lane & 15;

    // run the gather network on the lane index -> per-lane permutation,
    // then permute the weight rows to match (direction-proof).
    int pidx[16];
    ALLGATHER16I(pidx, k);

    float M0r[16], M1r[16], w1r[16];
#pragma unroll
    for (int j = 0; j < 16; ++j) {
        M0r[j] = M0[k * 16 + pidx[j]];
        M1r[j] = M1[k * 16 + pidx[j]];
        w1r[j] = wx1[k * 16 + pidx[j]];
    }
    const float b1r = b1[k];
    const float g0 = ln0_g[k], be0 = ln0_b[k];
    const float g1 = ln1_g[k], be1 = ln1_b[k];
    float h0 = 0.f, h1 = 0.f;
    const float* xpb = xp + b * TP_ * K_ + k;
    float xn0 = xpb[0];
    float xn1 = xpb[K_];
    for (int t = 0; t < TP_; ++t) {
        float h0g[16], h1g[16];
        ALLGATHER16F(h0g, h0);
        ALLGATHER16F(h1g, h1);
        float p0 = xn0, p1 = 0.f, p2 = 0.f, p3 = 0.f;
        xn0 = xn1;
        if (t + 2 < TP_) xn1 = xpb[(t + 2) * K_];
#pragma unroll
        for (int j = 0; j < 16; j += 4) {
            p0 = fmaf(M0r[j],     h0g[j],     p0);
            p1 = fmaf(M0r[j + 1], h0g[j + 1], p1);
            p2 = fmaf(M0r[j + 2], h0g[j + 2], p2);
            p3 = fmaf(M0r[j + 3], h0g[j + 3], p3);
        }
        const float pre = (p0 + p1) + (p2 + p3);
        float s1 = pre, s2 = pre * pre;
        RSUM16(s1);
        RSUM16(s2);
        float mu = s1 * 0.0625f;
        float var = s2 * 0.0625f - mu * mu;
        float r = rsqrtf(var + 1e-5f);
        h0 = tanh_f((pre - mu) * r * g0 + be0);

        float h0n[16];
        ALLGATHER16F(h0n, h0);
        float q0 = b1r, q1 = 0.f, q2 = 0.f, q3 = 0.f;
#pragma unroll
        for (int j = 0; j < 16; j += 4) {
            q0 = fmaf(w1r[j],     h0n[j],     q0);
            q1 = fmaf(w1r[j + 1], h0n[j + 1], q1);
            q2 = fmaf(w1r[j + 2], h0n[j + 2], q2);
            q3 = fmaf(w1r[j + 3], h0n[j + 3], q3);
        }
#pragma unroll
        for (int j = 0; j < 16; j += 4) {
            q0 = fmaf(M1r[j],     h1g[j],     q0);
            q1 = fmaf(M1r[j + 1], h1g[j + 1], q1);
            q2 = fmaf(M1r[j + 2], h1g[j + 2], q2);
            q3 = fmaf(M1r[j + 3], h1g[j + 3], q3);
        }
        const float pre1 = (q0 + q1) + (q2 + q3);
        s1 = pre1; s2 = pre1 * pre1;
        RSUM16(s1);
        RSUM16(s2);
        mu = s1 * 0.0625f;
        var = s2 * 0.0625f - mu * mu;
        r = rsqrtf(var + 1e-5f);
        h1 = tanh_f((pre1 - mu) * r * g1 + be1);
    }
    out[b * K_ + k] = h1;               // Z
    if (k == 0) out[256 + b] = 1.0f;    // alpha = softmax over size-1 axis
}

extern "C" void kernel_launch(void* const* d_in, const int* in_sizes, int n_in,
                              void* d_out, int out_size, void* d_ws, size_t ws_size,
                              hipStream_t stream) {
    const float* x       = (const float*)d_in[0];
    const float* sconv_w = (const float*)d_in[7];
    const float* sbn_g   = (const float*)d_in[9];
    const float* sbn_v   = (const float*)d_in[12];
    const float* dw_w    = (const float*)d_in[13];
    const float* dw_b    = (const float*)d_in[14];
    const float* wx1     = (const float*)d_in[29];
    const float* b1      = (const float*)d_in[32];
    const float* ln0_g   = (const float*)d_in[27];
    const float* ln0_b   = (const float*)d_in[28];
    const float* ln1_g   = (const float*)d_in[33];
    const float* ln1_b   = (const float*)d_in[34];
    float* ws = (float*)d_ws;
    float* out = (float*)d_out;

    P0 p;
    p.tconv_w = (const float*)d_in[1]; p.tconv_b = (const float*)d_in[2];
    p.tbn_g = (const float*)d_in[3]; p.tbn_b = (const float*)d_in[4];
    p.tbn_m = (const float*)d_in[5]; p.tbn_v = (const float*)d_in[6];
    p.sconv_b = (const float*)d_in[8];
    p.sbn_g = sbn_g; p.sbn_b = (const float*)d_in[10];
    p.sbn_m = (const float*)d_in[11]; p.sbn_v = sbn_v;
    p.pw_w = (const float*)d_in[15]; p.pw_b = (const float*)d_in[16];
    p.pbn_g = (const float*)d_in[17]; p.pbn_b = (const float*)d_in[18];
    p.pbn_m = (const float*)d_in[19]; p.pbn_v = (const float*)d_in[20];
    p.proj_w = (const float*)d_in[21]; p.proj_b = (const float*)d_in[22];
    p.wx0 = (const float*)d_in[23]; p.b0 = (const float*)d_in[26];
    p.L0 = (const float*)d_in[24]; p.ll0 = (const float*)d_in[25];
    p.L1 = (const float*)d_in[30]; p.ll1 = (const float*)d_in[31];
    p.ws = ws;

    k0a_setup<<<dim3(8), dim3(256), 0, stream>>>(p);
    k0b_repack<<<dim3(256), dim3(256), 0, stream>>>(sconv_w, sbn_g, sbn_v, ws + OFF_W2U);
    k1z<<<dim3(1250), dim3(256), 0, stream>>>((float4*)(ws + OFF_S2R));
    k1_part<<<dim3(1536), dim3(256), 0, stream>>>(x, ws + OFF_W1C, ws + OFF_TB2,
                                                  ws + OFF_W2U, ws + OFF_S2R);
    k2_dwpw<<<dim3(320), dim3(256), 0, stream>>>(ws + OFF_S2R, ws + OFF_SB2,
                                                 dw_w, dw_b, ws + OFF_PWC,
                                                 ws + OFF_PB2, ws + OFF_WP, ws + OFF_BP,
                                                 ws + OFF_XP);
    k3_scan<<<dim3(4), dim3(64), 0, stream>>>(ws + OFF_XP, ws + OFF_M0, ws + OFF_M1,
                                              wx1, b1, ln0_g, ln0_b, ln1_g, ln1_b, out);
}

// Round 5
// 658.970 us; speedup vs baseline: 2.5784x; 1.0375x over previous
//
#include <hip/hip_runtime.h>
#include <math.h>

#define B_ 16
#define C_ 129
#define T_ 2000
#define NF_ 40
#define ED_ 64
#define K_ 16
#define TP_ 500

#define CHUNK_C 6
#define NCHUNK 22

// workspace float offsets
#define OFF_W1C 0        // 1000   tconv weights * tbn scale
#define OFF_TB2 1000     // 40     folded tconv bias
#define OFF_SB2 1040     // 40     folded sconv bias
#define OFF_PWC 1088     // 3200   pw weights * pbn scale
#define OFF_PB2 4288     // 80     folded pw bias
#define OFF_WP  4368     // 1280   wx0 @ proj_w  (16x80)
#define OFF_BP  5648     // 16     wx0 @ proj_b + b0
#define OFF_M0  5664     // 256    L0@L0.T - exp(ll0) I
#define OFF_M1  5920     // 256    L1@L1.T - exp(ll1) I
#define OFF_W2U 8192     // 206400 repacked sconv weights [c][f][g] * sbn scale
#define OFF_XP  1495040  // 16*500*16  per-step cell0 input projection
#define OFF_S2R 1623040  // 1.28M  raw sconv accumulator (atomicAdd target)

__device__ __forceinline__ float elu_f(float x) {
    return x > 0.f ? x : (__expf(x) - 1.f);
}
__device__ __forceinline__ float tanh_f(float x) {
    float xc = fminf(fmaxf(x, -15.f), 15.f);
    float e2 = __expf(2.f * xc);
    return 1.f - 2.f / (e2 + 1.f);
}

// DPP helpers: row_ror:n ctrl = 0x120+n, rows of 16 lanes (aligned with our
// 16-lane batch groups). Direction-proofed: the weight permutation is derived
// at init by running the SAME network on the lane index.
#define DPPF(v, ctrl) __int_as_float(__builtin_amdgcn_update_dpp( \
    0, __float_as_int(v), (ctrl), 0xF, 0xF, false))
#define DPPI(v, ctrl) __builtin_amdgcn_update_dpp(0, (v), (ctrl), 0xF, 0xF, false)

#define ALLGATHER16F(dst, src) do {        \
    dst[0] = (src);                        \
    dst[1] = DPPF(dst[0], 0x121);          \
    dst[2] = DPPF(dst[0], 0x122);          \
    dst[3] = DPPF(dst[1], 0x122);          \
    dst[4] = DPPF(dst[0], 0x124);          \
    dst[5] = DPPF(dst[1], 0x124);          \
    dst[6] = DPPF(dst[2], 0x124);          \
    dst[7] = DPPF(dst[3], 0x124);          \
    dst[8] = DPPF(dst[0], 0x128);          \
    dst[9] = DPPF(dst[1], 0x128);          \
    dst[10] = DPPF(dst[2], 0x128);         \
    dst[11] = DPPF(dst[3], 0x128);         \
    dst[12] = DPPF(dst[4], 0x128);         \
    dst[13] = DPPF(dst[5], 0x128);         \
    dst[14] = DPPF(dst[6], 0x128);         \
    dst[15] = DPPF(dst[7], 0x128);         \
} while (0)

#define ALLGATHER16I(dst, src) do {        \
    dst[0] = (src);                        \
    dst[1] = DPPI(dst[0], 0x121);          \
    dst[2] = DPPI(dst[0], 0x122);          \
    dst[3] = DPPI(dst[1], 0x122);          \
    dst[4] = DPPI(dst[0], 0x124);          \
    dst[5] = DPPI(dst[1], 0x124);          \
    dst[6] = DPPI(dst[2], 0x124);          \
    dst[7] = DPPI(dst[3], 0x124);          \
    dst[8] = DPPI(dst[0], 0x128);          \
    dst[9] = DPPI(dst[1], 0x128);          \
    dst[10] = DPPI(dst[2], 0x128);         \
    dst[11] = DPPI(dst[3], 0x128);         \
    dst[12] = DPPI(dst[4], 0x128);         \
    dst[13] = DPPI(dst[5], 0x128);         \
    dst[14] = DPPI(dst[6], 0x128);         \
    dst[15] = DPPI(dst[7], 0x128);         \
} while (0)

// full-sum over each 16-lane row via rotate-add (direction-agnostic)
#define RSUM16(s) do {                     \
    s += DPPF(s, 0x128);                   \
    s += DPPF(s, 0x124);                   \
    s += DPPF(s, 0x122);                   \
    s += DPPF(s, 0x121);                   \
} while (0)

struct P0 {
    const float *tconv_w, *tconv_b, *tbn_g, *tbn_b, *tbn_m, *tbn_v;
    const float *sconv_b, *sbn_g, *sbn_b, *sbn_m, *sbn_v;
    const float *pw_w, *pw_b, *pbn_g, *pbn_b, *pbn_m, *pbn_v;
    const float *proj_w, *proj_b, *wx0, *b0, *L0, *ll0, *L1, *ll1;
    float* ws;
};

__global__ __launch_bounds__(256) void k0a_setup(P0 p) {
    const int tid = blockIdx.x * 256 + threadIdx.x;
    const int stride = gridDim.x * 256;
    float* ws = p.ws;
    const float eps = 1e-5f;
    for (int e = tid; e < 1000; e += stride) {
        const int f = e / 25;
        const float inv = p.tbn_g[f] / sqrtf(p.tbn_v[f] + eps);
        ws[OFF_W1C + e] = p.tconv_w[e] * inv;
    }
    for (int f = tid; f < NF_; f += stride) {
        const float inv = p.tbn_g[f] / sqrtf(p.tbn_v[f] + eps);
        ws[OFF_TB2 + f] = p.tconv_b[f] * inv + p.tbn_b[f] - p.tbn_m[f] * inv;
        const float sinv = p.sbn_g[f] / sqrtf(p.sbn_v[f] + eps);
        ws[OFF_SB2 + f] = p.sconv_b[f] * sinv + p.sbn_b[f] - p.sbn_m[f] * sinv;
    }
    for (int e = tid; e < 3200; e += stride) {
        const int g = e / 40;
        const float pinv = p.pbn_g[g] / sqrtf(p.pbn_v[g] + eps);
        ws[OFF_PWC + e] = p.pw_w[e] * pinv;
    }
    for (int g = tid; g < 80; g += stride) {
        const float pinv = p.pbn_g[g] / sqrtf(p.pbn_v[g] + eps);
        ws[OFF_PB2 + g] = p.pw_b[g] * pinv + p.pbn_b[g] - p.pbn_m[g] * pinv;
    }
    for (int e = tid; e < 1280; e += stride) {
        const int k = e / 80, g = e - k * 80;
        float a = 0.f;
        for (int ee = 0; ee < ED_; ++ee)
            a = fmaf(p.wx0[k * ED_ + ee], p.proj_w[ee * 80 + g], a);
        ws[OFF_WP + e] = a;
    }
    for (int k = tid; k < K_; k += stride) {
        float a = p.b0[k];
        for (int ee = 0; ee < ED_; ++ee)
            a = fmaf(p.wx0[k * ED_ + ee], p.proj_b[ee], a);
        ws[OFF_BP + k] = a;
    }
    for (int e = tid; e < 256; e += stride) {
        const int k = e >> 4, j = e & 15;
        float a0 = 0.f, a1 = 0.f;
        for (int i = 0; i < 16; ++i) {
            a0 = fmaf(p.L0[k * 16 + i], p.L0[j * 16 + i], a0);
            a1 = fmaf(p.L1[k * 16 + i], p.L1[j * 16 + i], a1);
        }
        if (k == j) { a0 -= expf(p.ll0[0]); a1 -= expf(p.ll1[0]); }
        ws[OFF_M0 + e] = a0;
        ws[OFF_M1 + e] = a1;
    }
}

// repack sconv_w[g][f][c] -> w2u[c][f][g], scaled by sbn inv (wave-uniform s_loads)
__global__ __launch_bounds__(256) void k0b_repack(
    const float* __restrict__ sconv_w, const float* __restrict__ sbn_g,
    const float* __restrict__ sbn_v, float* __restrict__ w2u) {
    const int total = C_ * 1600;
    for (int e = blockIdx.x * 256 + threadIdx.x; e < total; e += 256 * 256) {
        const int c = e / 1600;
        int r = e - c * 1600;
        const int f = r / 40;
        const int g = r - f * 40;
        const float sinv = sbn_g[g] / sqrtf(sbn_v[g] + 1e-5f);
        w2u[e] = sconv_w[g * (NF_ * C_) + f * C_ + c] * sinv;
    }
}

// zero the raw accumulator (ws is re-poisoned 0xAA before every launch)
__global__ __launch_bounds__(256) void k1z(float4* __restrict__ p) {
    const int i = blockIdx.x * 256 + threadIdx.x;
    if (i < 320000) p[i] = make_float4(0.f, 0.f, 0.f, 0.f);
}

// Fused tconv(25)+BN+ELU+sconv partial over a 6-channel chunk.
// grid = b(16) x ttile(8 x 256) x chunk(22) = 2816 blocks -> ~11 blocks/CU
// nominal; VGPR=40, LDS=6.7KB so wave cap is SGPR-bound ~28/CU.
__global__ __launch_bounds__(256) void k1_part(
    const float* __restrict__ x, const float* __restrict__ w1c,
    const float* __restrict__ tb2, const float* __restrict__ w2u,
    float* __restrict__ s2raw) {
    __shared__ float xs[CHUNK_C * 280];
    const int tid = threadIdx.x;
    const int chunk = blockIdx.x % NCHUNK;
    const int tmp = blockIdx.x / NCHUNK;
    const int tile = tmp & 7;
    const int b = tmp >> 3;
    const int c0 = chunk * CHUNK_C;
    const int cc = (C_ - c0) < CHUNK_C ? (C_ - c0) : CHUNK_C;
    const int t0 = tile << 8;

    const int tot = cc * 280;
    for (int e = tid; e < tot; e += 256) {
        const int cl = e / 280;
        const int i = e - cl * 280;
        const int t = t0 - 12 + i;
        float v = 0.f;
        if ((unsigned)t < (unsigned)T_) v = x[(b * C_ + c0 + cl) * T_ + t];
        xs[e] = v;
    }
    __syncthreads();

    float acc[NF_];
#pragma unroll
    for (int g = 0; g < NF_; ++g) acc[g] = 0.f;

    const int tt = tid;
    for (int cl = 0; cl < cc; ++cl) {
        float xr[25];
#pragma unroll
        for (int kk = 0; kk < 25; ++kk) xr[kk] = xs[cl * 280 + tt + kk];
        const float* w2p = w2u + (c0 + cl) * 1600;
#pragma unroll 2
        for (int f = 0; f < NF_; ++f) {
            const float* w1p = w1c + f * 25;
            float a0 = tb2[f], a1 = 0.f, a2 = 0.f, a3 = 0.f;
#pragma unroll
            for (int kk = 0; kk < 24; kk += 4) {
                a0 = fmaf(w1p[kk],     xr[kk],     a0);
                a1 = fmaf(w1p[kk + 1], xr[kk + 1], a1);
                a2 = fmaf(w1p[kk + 2], xr[kk + 2], a2);
                a3 = fmaf(w1p[kk + 3], xr[kk + 3], a3);
            }
            a0 = fmaf(w1p[24], xr[24], a0);
            const float e = elu_f((a0 + a1) + (a2 + a3));
#pragma unroll
            for (int g = 0; g < NF_; ++g)
                acc[g] = fmaf(w2p[f * 40 + g], e, acc[g]);
        }
    }
    const int t = t0 + tt;
    if (t < T_) {
#pragma unroll
        for (int g = 0; g < NF_; ++g)
            atomicAdd(&s2raw[(b * NF_ + g) * T_ + t], acc[g]);
    }
}

// Fused: bias+ELU on s2raw at stage time, depthwise(15) + pointwise(80x40)
// + BN + ELU + pool4 + (proj∘wx0) -> xp[b][tp][k]
__global__ __launch_bounds__(256) void k2_dwpw(
    const float* __restrict__ s2raw, const float* __restrict__ sb2,
    const float* __restrict__ dw_w, const float* __restrict__ dw_b,
    const float* __restrict__ pwc, const float* __restrict__ pb2,
    const float* __restrict__ WP, const float* __restrict__ bp,
    float* __restrict__ xp) {
    __shared__ float st[NF_ * 114];
    __shared__ float dwo[NF_ * 100];
    __shared__ float dwwl[NF_ * 15];
    __shared__ float dwbl[NF_];
    __shared__ float pwcl[80 * 40];
    __shared__ float pb2l[80];
    __shared__ float WPl[K_ * 80];
    __shared__ float bpl[K_];
    __shared__ float po[80 * 25];
    const int tid = threadIdx.x;
    const int b = blockIdx.x / 20;
    const int tp0 = (blockIdx.x % 20) * 25;
    const int tbase = tp0 * 4 - 7;
    for (int e = tid; e < NF_ * 114; e += 256) {
        const int f = e / 114;
        const int i = e - f * 114;
        const int t = tbase + i;
        float v = 0.f;
        if ((unsigned)t < (unsigned)T_)
            v = elu_f(s2raw[(b * NF_ + f) * T_ + t] + sb2[f]);
        st[e] = v;
    }
    for (int e = tid; e < 600; e += 256) dwwl[e] = dw_w[e];
    for (int e = tid; e < 3200; e += 256) pwcl[e] = pwc[e];
    for (int e = tid; e < 1280; e += 256) WPl[e] = WP[e];
    if (tid < NF_) dwbl[tid] = dw_b[tid];
    if (tid < 80) pb2l[tid] = pb2[tid];
    if (tid < K_) bpl[tid] = bp[tid];
    __syncthreads();
    for (int e = tid; e < 4000; e += 256) {
        const int f = e / 100;
        const int tq = e - f * 100;
        float a = dwbl[f];
#pragma unroll
        for (int kk = 0; kk < 15; ++kk)
            a = fmaf(dwwl[f * 15 + kk], st[f * 114 + tq + kk], a);
        dwo[e] = a;
    }
    __syncthreads();
    for (int e = tid; e < 2000; e += 256) {
        const int g = e / 25;
        const int tp = e - g * 25;
        float sum = 0.f;
#pragma unroll
        for (int dt = 0; dt < 4; ++dt) {
            float a = pb2l[g];
            for (int f = 0; f < NF_; ++f)
                a = fmaf(pwcl[g * 40 + f], dwo[f * 100 + tp * 4 + dt], a);
            sum += elu_f(a);
        }
        po[e] = sum * 0.25f;
    }
    __syncthreads();
    for (int e = tid; e < 400; e += 256) {
        const int tp = e >> 4;
        const int k = e & 15;
        float a = bpl[k];
        for (int g = 0; g < 80; ++g)
            a = fmaf(WPl[k * 80 + g], po[g * 25 + tp], a);
        xp[(b * TP_ + tp0 + tp) * K_ + k] = a;
    }
}

// Sequential 500-step scan, DPP-only cross-lane, software-pipelined by one
// step: iteration t computes cell1(t) and cell0(t+1) as two independent
// dependency chains (cell0's recurrence involves only h0). 4 blocks x 1 wave;
// each wave = 4 batches x 16 k (16-lane groups == DPP rows).
__global__ __launch_bounds__(64, 1) void k3_scan(
    const float* __restrict__ xp, const float* __restrict__ M0,
    const float* __restrict__ M1, const float* __restrict__ wx1,
    const float* __restrict__ b1, const float* __restrict__ ln0_g,
    const float* __restrict__ ln0_b, const float* __restrict__ ln1_g,
    const float* __restrict__ ln1_b, float* __restrict__ out) {
    const int lane = threadIdx.x;
    const int b = blockIdx.x * 4 + (lane >> 4);
    const int k = lane & 15;

    // run the gather network on the lane index -> per-lane permutation,
    // then permute the weight rows to match (direction-proof).
    int pidx[16];
    ALLGATHER16I(pidx, k);

    float M0r[16], M1r[16], w1r[16];
#pragma unroll
    for (int j = 0; j < 16; ++j) {
        M0r[j] = M0[k * 16 + pidx[j]];
        M1r[j] = M1[k * 16 + pidx[j]];
        w1r[j] = wx1[k * 16 + pidx[j]];
    }
    const float b1r = b1[k];
    const float g0 = ln0_g[k], be0 = ln0_b[k];
    const float g1 = ln1_g[k], be1 = ln1_b[k];
    const float* xpb = xp + b * TP_ * K_ + k;

    // prologue: h0_0 = cell0(x_0, h0=0)  (matvec term vanishes)
    float x0 = xpb[0];
    {
        float s1 = x0, s2 = x0 * x0;
        RSUM16(s1);
        RSUM16(s2);
        const float mu = s1 * 0.0625f;
        const float var = s2 * 0.0625f - mu * mu;
        const float r = rsqrtf(var + 1e-5f);
        x0 = tanh_f((x0 - mu) * r * g0 + be0);
    }
    float h0c = x0;   // h0 at step t (t=0 now)
    float h1c = 0.f;  // h1 at step t-1

    // x prefetch ring, depth 4: slot (t+1)&3 holds x_{t+1}
    float xn[4];
    xn[1] = xpb[1 * K_];
    xn[2] = xpb[2 * K_];
    xn[3] = xpb[3 * K_];
    xn[0] = xpb[4 * K_];

    for (int t = 0; t < TP_; ++t) {
        float h0g[16], h1g[16];
        ALLGATHER16F(h0g, h0c);
        ALLGATHER16F(h1g, h1c);
        const int slot = (t + 1) & 3;
        const float xv = xn[slot];
        int tf = t + 5;
        if (tf > TP_ - 1) tf = TP_ - 1;
        xn[slot] = xpb[tf * K_];

        // ---- chain B: cell1 at step t: h1c = f(h0_t, h1_{t-1}) ----
        float q0 = b1r, q1 = 0.f, q2 = 0.f, q3 = 0.f;
#pragma unroll
        for (int j = 0; j < 16; j += 4) {
            q0 = fmaf(w1r[j],     h0g[j],     q0);
            q1 = fmaf(w1r[j + 1], h0g[j + 1], q1);
            q2 = fmaf(w1r[j + 2], h0g[j + 2], q2);
            q3 = fmaf(w1r[j + 3], h0g[j + 3], q3);
        }
#pragma unroll
        for (int j = 0; j < 16; j += 4) {
            q0 = fmaf(M1r[j],     h1g[j],     q0);
            q1 = fmaf(M1r[j + 1], h1g[j + 1], q1);
            q2 = fmaf(M1r[j + 2], h1g[j + 2], q2);
            q3 = fmaf(M1r[j + 3], h1g[j + 3], q3);
        }
        const float pre1 = (q0 + q1) + (q2 + q3);
        float u1 = pre1, u2 = pre1 * pre1;
        RSUM16(u1);
        RSUM16(u2);
        const float mu1 = u1 * 0.0625f;
        const float var1 = u2 * 0.0625f - mu1 * mu1;
        const float r1 = rsqrtf(var1 + 1e-5f);
        const float h1n = tanh_f((pre1 - mu1) * r1 * g1 + be1);

        // ---- chain A: cell0 at step t+1: h0n = f(x_{t+1}, h0_t) ----
        float p0 = xv, p1 = 0.f, p2 = 0.f, p3 = 0.f;
#pragma unroll
        for (int j = 0; j < 16; j += 4) {
            p0 = fmaf(M0r[j],     h0g[j],     p0);
            p1 = fmaf(M0r[j + 1], h0g[j + 1], p1);
            p2 = fmaf(M0r[j + 2], h0g[j + 2], p2);
            p3 = fmaf(M0r[j + 3], h0g[j + 3], p3);
        }
        const float pre0 = (p0 + p1) + (p2 + p3);
        float s1 = pre0, s2 = pre0 * pre0;
        RSUM16(s1);
        RSUM16(s2);
        const float mu0 = s1 * 0.0625f;
        const float var0 = s2 * 0.0625f - mu0 * mu0;
        const float r0 = rsqrtf(var0 + 1e-5f);
        const float h0n = tanh_f((pre0 - mu0) * r0 * g0 + be0);

        h1c = h1n;
        h0c = h0n;  // at t=TP-1 this is h0_500, unused
    }
    out[b * K_ + k] = h1c;              // Z = h1 after step 499
    if (k == 0) out[256 + b] = 1.0f;    // alpha = softmax over size-1 axis
}

extern "C" void kernel_launch(void* const* d_in, const int* in_sizes, int n_in,
                              void* d_out, int out_size, void* d_ws, size_t ws_size,
                              hipStream_t stream) {
    const float* x       = (const float*)d_in[0];
    const float* sconv_w = (const float*)d_in[7];
    const float* sbn_g   = (const float*)d_in[9];
    const float* sbn_v   = (const float*)d_in[12];
    const float* dw_w    = (const float*)d_in[13];
    const float* dw_b    = (const float*)d_in[14];
    const float* wx1     = (const float*)d_in[29];
    const float* b1      = (const float*)d_in[32];
    const float* ln0_g   = (const float*)d_in[27];
    const float* ln0_b   = (const float*)d_in[28];
    const float* ln1_g   = (const float*)d_in[33];
    const float* ln1_b   = (const float*)d_in[34];
    float* ws = (float*)d_ws;
    float* out = (float*)d_out;

    P0 p;
    p.tconv_w = (const float*)d_in[1]; p.tconv_b = (const float*)d_in[2];
    p.tbn_g = (const float*)d_in[3]; p.tbn_b = (const float*)d_in[4];
    p.tbn_m = (const float*)d_in[5]; p.tbn_v = (const float*)d_in[6];
    p.sconv_b = (const float*)d_in[8];
    p.sbn_g = sbn_g; p.sbn_b = (const float*)d_in[10];
    p.sbn_m = (const float*)d_in[11]; p.sbn_v = sbn_v;
    p.pw_w = (const float*)d_in[15]; p.pw_b = (const float*)d_in[16];
    p.pbn_g = (const float*)d_in[17]; p.pbn_b = (const float*)d_in[18];
    p.pbn_m = (const float*)d_in[19]; p.pbn_v = (const float*)d_in[20];
    p.proj_w = (const float*)d_in[21]; p.proj_b = (const float*)d_in[22];
    p.wx0 = (const float*)d_in[23]; p.b0 = (const float*)d_in[26];
    p.L0 = (const float*)d_in[24]; p.ll0 = (const float*)d_in[25];
    p.L1 = (const float*)d_in[30]; p.ll1 = (const float*)d_in[31];
    p.ws = ws;

    k0a_setup<<<dim3(8), dim3(256), 0, stream>>>(p);
    k0b_repack<<<dim3(256), dim3(256), 0, stream>>>(sconv_w, sbn_g, sbn_v, ws + OFF_W2U);
    k1z<<<dim3(1250), dim3(256), 0, stream>>>((float4*)(ws + OFF_S2R));
    k1_part<<<dim3(2816), dim3(256), 0, stream>>>(x, ws + OFF_W1C, ws + OFF_TB2,
                                                  ws + OFF_W2U, ws + OFF_S2R);
    k2_dwpw<<<dim3(320), dim3(256), 0, stream>>>(ws + OFF_S2R, ws + OFF_SB2,
                                                 dw_w, dw_b, ws + OFF_PWC,
                                                 ws + OFF_PB2, ws + OFF_WP, ws + OFF_BP,
                                                 ws + OFF_XP);
    k3_scan<<<dim3(4), dim3(64), 0, stream>>>(ws + OFF_XP, ws + OFF_M0, ws + OFF_M1,
                                              wx1, b1, ln0_g, ln0_b, ln1_g, ln1_b, out);
}

// Round 6
// 574.604 us; speedup vs baseline: 2.9570x; 1.1468x over previous
//
#include <hip/hip_runtime.h>
#include <math.h>

#define B_ 16
#define C_ 129
#define T_ 2000
#define NF_ 40
#define ED_ 64
#define K_ 16
#define TP_ 500

// workspace float offsets
#define OFF_W1C 0        // 1000   tconv weights * tbn scale
#define OFF_TB2 1000     // 40     folded tconv bias
#define OFF_SB2 1040     // 40     folded sconv bias
#define OFF_PWC 1088     // 3200   pw weights * pbn scale
#define OFF_PB2 4288     // 80     folded pw bias
#define OFF_WP  4368     // 1280   wx0 @ proj_w  (16x80)
#define OFF_BP  5648     // 16     wx0 @ proj_b + b0
#define OFF_M0  5664     // 256    L0@L0.T - exp(ll0) I
#define OFF_M1  5920     // 256    L1@L1.T - exp(ll1) I
#define OFF_W2U 8192     // bf16 A-frag prepack of sconv weights: 396288 ushort (792KB)
#define OFF_XP  1495040  // 16*500*16  per-step cell0 input projection
#define OFF_S2R 1623040  // 1.28M  raw sconv accumulator (atomicAdd target)

typedef __attribute__((ext_vector_type(8))) short s8v;
typedef __attribute__((ext_vector_type(4))) float f4v;

__device__ __forceinline__ float elu_f(float x) {
    return x > 0.f ? x : (__expf(x) - 1.f);
}
__device__ __forceinline__ float tanh_f(float x) {
    float xc = fminf(fmaxf(x, -15.f), 15.f);
    float e2 = __expf(2.f * xc);
    return 1.f - 2.f / (e2 + 1.f);
}
// round-half-up fp32 -> bf16 (values here are finite/small; bias is ±0.5ulp random)
__device__ __forceinline__ unsigned bfr(float v) {
    return (__float_as_uint(v) + 0x8000u) >> 16;
}

// DPP helpers (k3): row_ror:n ctrl = 0x120+n, rows of 16 lanes.
#define DPPF(v, ctrl) __int_as_float(__builtin_amdgcn_update_dpp( \
    0, __float_as_int(v), (ctrl), 0xF, 0xF, false))
#define DPPI(v, ctrl) __builtin_amdgcn_update_dpp(0, (v), (ctrl), 0xF, 0xF, false)

#define ALLGATHER16F(dst, src) do {        \
    dst[0] = (src);                        \
    dst[1] = DPPF(dst[0], 0x121);          \
    dst[2] = DPPF(dst[0], 0x122);          \
    dst[3] = DPPF(dst[1], 0x122);          \
    dst[4] = DPPF(dst[0], 0x124);          \
    dst[5] = DPPF(dst[1], 0x124);          \
    dst[6] = DPPF(dst[2], 0x124);          \
    dst[7] = DPPF(dst[3], 0x124);          \
    dst[8] = DPPF(dst[0], 0x128);          \
    dst[9] = DPPF(dst[1], 0x128);          \
    dst[10] = DPPF(dst[2], 0x128);         \
    dst[11] = DPPF(dst[3], 0x128);         \
    dst[12] = DPPF(dst[4], 0x128);         \
    dst[13] = DPPF(dst[5], 0x128);         \
    dst[14] = DPPF(dst[6], 0x128);         \
    dst[15] = DPPF(dst[7], 0x128);         \
} while (0)

#define ALLGATHER16I(dst, src) do {        \
    dst[0] = (src);                        \
    dst[1] = DPPI(dst[0], 0x121);          \
    dst[2] = DPPI(dst[0], 0x122);          \
    dst[3] = DPPI(dst[1], 0x122);          \
    dst[4] = DPPI(dst[0], 0x124);          \
    dst[5] = DPPI(dst[1], 0x124);          \
    dst[6] = DPPI(dst[2], 0x124);          \
    dst[7] = DPPI(dst[3], 0x124);          \
    dst[8] = DPPI(dst[0], 0x128);          \
    dst[9] = DPPI(dst[1], 0x128);          \
    dst[10] = DPPI(dst[2], 0x128);         \
    dst[11] = DPPI(dst[3], 0x128);         \
    dst[12] = DPPI(dst[4], 0x128);         \
    dst[13] = DPPI(dst[5], 0x128);         \
    dst[14] = DPPI(dst[6], 0x128);         \
    dst[15] = DPPI(dst[7], 0x128);         \
} while (0)

#define RSUM16(s) do {                     \
    s += DPPF(s, 0x128);                   \
    s += DPPF(s, 0x124);                   \
    s += DPPF(s, 0x122);                   \
    s += DPPF(s, 0x121);                   \
} while (0)

struct P0 {
    const float *tconv_w, *tconv_b, *tbn_g, *tbn_b, *tbn_m, *tbn_v;
    const float *sconv_b, *sbn_g, *sbn_b, *sbn_m, *sbn_v;
    const float *pw_w, *pw_b, *pbn_g, *pbn_b, *pbn_m, *pbn_v;
    const float *proj_w, *proj_b, *wx0, *b0, *L0, *ll0, *L1, *ll1;
    float* ws;
};

__global__ __launch_bounds__(256) void k0a_setup(P0 p) {
    const int tid = blockIdx.x * 256 + threadIdx.x;
    const int stride = gridDim.x * 256;
    float* ws = p.ws;
    const float eps = 1e-5f;
    for (int e = tid; e < 1000; e += stride) {
        const int f = e / 25;
        const float inv = p.tbn_g[f] / sqrtf(p.tbn_v[f] + eps);
        ws[OFF_W1C + e] = p.tconv_w[e] * inv;
    }
    for (int f = tid; f < NF_; f += stride) {
        const float inv = p.tbn_g[f] / sqrtf(p.tbn_v[f] + eps);
        ws[OFF_TB2 + f] = p.tconv_b[f] * inv + p.tbn_b[f] - p.tbn_m[f] * inv;
        const float sinv = p.sbn_g[f] / sqrtf(p.sbn_v[f] + eps);
        ws[OFF_SB2 + f] = p.sconv_b[f] * sinv + p.sbn_b[f] - p.sbn_m[f] * sinv;
    }
    for (int e = tid; e < 3200; e += stride) {
        const int g = e / 40;
        const float pinv = p.pbn_g[g] / sqrtf(p.pbn_v[g] + eps);
        ws[OFF_PWC + e] = p.pw_w[e] * pinv;
    }
    for (int g = tid; g < 80; g += stride) {
        const float pinv = p.pbn_g[g] / sqrtf(p.pbn_v[g] + eps);
        ws[OFF_PB2 + g] = p.pw_b[g] * pinv + p.pbn_b[g] - p.pbn_m[g] * pinv;
    }
    for (int e = tid; e < 1280; e += stride) {
        const int k = e / 80, g = e - k * 80;
        float a = 0.f;
        for (int ee = 0; ee < ED_; ++ee)
            a = fmaf(p.wx0[k * ED_ + ee], p.proj_w[ee * 80 + g], a);
        ws[OFF_WP + e] = a;
    }
    for (int k = tid; k < K_; k += stride) {
        float a = p.b0[k];
        for (int ee = 0; ee < ED_; ++ee)
            a = fmaf(p.wx0[k * ED_ + ee], p.proj_b[ee], a);
        ws[OFF_BP + k] = a;
    }
    for (int e = tid; e < 256; e += stride) {
        const int k = e >> 4, j = e & 15;
        float a0 = 0.f, a1 = 0.f;
        for (int i = 0; i < 16; ++i) {
            a0 = fmaf(p.L0[k * 16 + i], p.L0[j * 16 + i], a0);
            a1 = fmaf(p.L1[k * 16 + i], p.L1[j * 16 + i], a1);
        }
        if (k == j) { a0 -= expf(p.ll0[0]); a1 -= expf(p.ll1[0]); }
        ws[OFF_M0 + e] = a0;
        ws[OFF_M1 + e] = a1;
    }
}

// Prepack sconv weights * sbn scale into bf16 MFMA A-fragment order:
// element j of lane L for (c, m-tile mt, k-chunk kc):
//   g = mt*16 + (L&15),  f = kc*32 + (L>>4)*8 + j   (zero-padded g>=40, f>=40)
// flat: w2b[(((c*3+mt)*2+kc)*64 + L)*8 + j]
__global__ __launch_bounds__(256) void k0b_repack(
    const float* __restrict__ sconv_w, const float* __restrict__ sbn_g,
    const float* __restrict__ sbn_v, unsigned short* __restrict__ w2b) {
    const int e = blockIdx.x * 256 + threadIdx.x;
    if (e >= C_ * 3 * 2 * 64) return;
    const int c = e / 384;
    int r = e - c * 384;
    const int mt = r >> 7; r &= 127;
    const int kc = r >> 6;
    const int lane = r & 63;
    const int g = mt * 16 + (lane & 15);
    const float sinv = (g < NF_) ? sbn_g[g] * rsqrtf(sbn_v[g] + 1e-5f) : 0.f;
    unsigned short o[8];
#pragma unroll
    for (int j = 0; j < 8; ++j) {
        const int f = kc * 32 + (lane >> 4) * 8 + j;
        float v = 0.f;
        if (g < NF_ && f < NF_) v = sconv_w[g * (NF_ * C_) + f * C_ + c] * sinv;
        o[j] = (unsigned short)bfr(v);
    }
    unsigned short* dst = w2b + (size_t)e * 8;
#pragma unroll
    for (int j = 0; j < 8; ++j) dst[j] = o[j];
}

// zero the raw accumulator (ws is re-poisoned 0xAA before every launch)
__global__ __launch_bounds__(256) void k1z(float4* __restrict__ p) {
    const int i = blockIdx.x * 256 + threadIdx.x;
    if (i < 320000) p[i] = make_float4(0.f, 0.f, 0.f, 0.f);
}

// Fused tconv(25)+BN+ELU (fp32 VALU) + sconv via bf16 MFMA 16x16x32.
// grid = b(16) x ttile(8 x 256) x csplit(8) = 1024 blocks, 4 waves each.
// Wave w owns t = t0+64w+lane; writes its V panel (bf16, B-frag order) to a
// PRIVATE LDS region -> zero barriers in the c-loop (wave-synchronous LDS).
// Exactly one __syncthreads per block (after cooperative x staging).
__global__ __launch_bounds__(256, 3) void k1_mfma(
    const float* __restrict__ x, const float* __restrict__ w1c,
    const float* __restrict__ tb2, const unsigned short* __restrict__ w2b,
    float* __restrict__ s2raw) {
    __shared__ float xs[17 * 280];          // staged x rows (t0-12 .. t0+267)
    __shared__ unsigned int vsI[8192];      // 4 waves x [nt4][oct8][n16][16B]

    const int tid = threadIdx.x;
    const int split = blockIdx.x & 7;
    const int tile = (blockIdx.x >> 3) & 7;
    const int b = blockIdx.x >> 6;
    const int c0 = (split * C_) >> 3;
    const int c1 = ((split + 1) * C_) >> 3;
    const int cc = c1 - c0;
    const int t0 = tile << 8;
    const int w = tid >> 6;
    const int lane = tid & 63;
    const int n = lane & 15;
    const int q = lane >> 4;
    const int wb = w << 11;                 // wave base in vsI words (2048)

    // zero V panels (pad octets 5-7 must be 0; real octets rewritten per c)
    for (int i = tid; i < 8192; i += 256) vsI[i] = 0u;
    // stage x rows for this block's channel range
    for (int e = tid; e < cc * 280; e += 256) {
        const int cl = e / 280;
        const int i = e - cl * 280;
        const int t = t0 - 12 + i;
        float v = 0.f;
        if ((unsigned)t < (unsigned)T_) v = x[(b * C_ + c0 + cl) * T_ + t];
        xs[e] = v;
    }
    __syncthreads();

    f4v acc[4][3];
#pragma unroll
    for (int nt = 0; nt < 4; ++nt)
#pragma unroll
        for (int mt = 0; mt < 3; ++mt) acc[nt][mt] = (f4v)0.f;

    const s8v* w2b8 = (const s8v*)w2b;

    for (int cl = 0; cl < cc; ++cl) {
        const int c = c0 + cl;
        // prefetch A-frags for this channel (6 x 16B, coalesced)
        s8v af[3][2];
#pragma unroll
        for (int mt = 0; mt < 3; ++mt)
#pragma unroll
            for (int kc = 0; kc < 2; ++kc)
                af[mt][kc] = w2b8[((c * 3 + mt) * 2 + kc) * 64 + lane];

        // tconv inputs for this lane's t
        float xr[25];
#pragma unroll
        for (int k = 0; k < 25; ++k) xr[k] = xs[cl * 280 + tid + k];

        // tconv + BN + ELU for all 40 filters; pack bf16 pairs into V panel.
        // writer: nt == q (lane's t-subtile), word = wb + (q*8+oct)*64 + n*4 + pair
        float ep = 0.f;
#pragma unroll 4
        for (int f = 0; f < NF_; ++f) {
            const float* w1p = w1c + f * 25;
            float a0 = tb2[f], a1 = 0.f, a2 = 0.f, a3 = 0.f;
#pragma unroll
            for (int kk = 0; kk < 24; kk += 4) {
                a0 = fmaf(w1p[kk],     xr[kk],     a0);
                a1 = fmaf(w1p[kk + 1], xr[kk + 1], a1);
                a2 = fmaf(w1p[kk + 2], xr[kk + 2], a2);
                a3 = fmaf(w1p[kk + 3], xr[kk + 3], a3);
            }
            a0 = fmaf(w1p[24], xr[24], a0);
            const float ev = elu_f((a0 + a1) + (a2 + a3));
            if ((f & 1) == 0) {
                ep = ev;
            } else {
                const unsigned pk = bfr(ep) |
                    ((__float_as_uint(ev) + 0x8000u) & 0xFFFF0000u);
                const int f0 = f - 1;
                vsI[wb + ((q * 8 + (f0 >> 3)) << 6) + (n << 2) + ((f0 & 7) >> 1)] = pk;
            }
        }
        __builtin_amdgcn_wave_barrier();   // order LDS writes before reads (same wave)

        // MFMA: for each n-subtile, read B-frags (k=f contraction) + accumulate
#pragma unroll
        for (int nt = 0; nt < 4; ++nt) {
            const s8v b0 = *(const s8v*)&vsI[wb + ((nt * 8 + q) << 6) + (n << 2)];
            const s8v b1 = *(const s8v*)&vsI[wb + ((nt * 8 + 4 + q) << 6) + (n << 2)];
#pragma unroll
            for (int mt = 0; mt < 3; ++mt) {
                acc[nt][mt] = __builtin_amdgcn_mfma_f32_16x16x32_bf16(
                    af[mt][0], b0, acc[nt][mt], 0, 0, 0);
                acc[nt][mt] = __builtin_amdgcn_mfma_f32_16x16x32_bf16(
                    af[mt][1], b1, acc[nt][mt], 0, 0, 0);
            }
        }
        __builtin_amdgcn_wave_barrier();   // reads of panel done before next c's writes
    }

    // epilogue: C/D layout col=lane&15 (t), row=quad*4+reg (g)  [m89-verified]
#pragma unroll
    for (int nt = 0; nt < 4; ++nt) {
        const int t = t0 + w * 64 + nt * 16 + n;
        if (t >= T_) continue;
#pragma unroll
        for (int mt = 0; mt < 3; ++mt) {
#pragma unroll
            for (int r = 0; r < 4; ++r) {
                const int g = mt * 16 + q * 4 + r;
                if (g < NF_)
                    atomicAdd(&s2raw[(b * NF_ + g) * T_ + t], acc[nt][mt][r]);
            }
        }
    }
}

// Fused: bias+ELU on s2raw at stage time, depthwise(15) + pointwise(80x40)
// + BN + ELU + pool4 + (proj∘wx0) -> xp[b][tp][k]
__global__ __launch_bounds__(256) void k2_dwpw(
    const float* __restrict__ s2raw, const float* __restrict__ sb2,
    const float* __restrict__ dw_w, const float* __restrict__ dw_b,
    const float* __restrict__ pwc, const float* __restrict__ pb2,
    const float* __restrict__ WP, const float* __restrict__ bp,
    float* __restrict__ xp) {
    __shared__ float st[NF_ * 114];
    __shared__ float dwo[NF_ * 100];
    __shared__ float dwwl[NF_ * 15];
    __shared__ float dwbl[NF_];
    __shared__ float pwcl[80 * 40];
    __shared__ float pb2l[80];
    __shared__ float WPl[K_ * 80];
    __shared__ float bpl[K_];
    __shared__ float po[80 * 25];
    const int tid = threadIdx.x;
    const int b = blockIdx.x / 20;
    const int tp0 = (blockIdx.x % 20) * 25;
    const int tbase = tp0 * 4 - 7;
    for (int e = tid; e < NF_ * 114; e += 256) {
        const int f = e / 114;
        const int i = e - f * 114;
        const int t = tbase + i;
        float v = 0.f;
        if ((unsigned)t < (unsigned)T_)
            v = elu_f(s2raw[(b * NF_ + f) * T_ + t] + sb2[f]);
        st[e] = v;
    }
    for (int e = tid; e < 600; e += 256) dwwl[e] = dw_w[e];
    for (int e = tid; e < 3200; e += 256) pwcl[e] = pwc[e];
    for (int e = tid; e < 1280; e += 256) WPl[e] = WP[e];
    if (tid < NF_) dwbl[tid] = dw_b[tid];
    if (tid < 80) pb2l[tid] = pb2[tid];
    if (tid < K_) bpl[tid] = bp[tid];
    __syncthreads();
    for (int e = tid; e < 4000; e += 256) {
        const int f = e / 100;
        const int tq = e - f * 100;
        float a = dwbl[f];
#pragma unroll
        for (int kk = 0; kk < 15; ++kk)
            a = fmaf(dwwl[f * 15 + kk], st[f * 114 + tq + kk], a);
        dwo[e] = a;
    }
    __syncthreads();
    for (int e = tid; e < 2000; e += 256) {
        const int g = e / 25;
        const int tp = e - g * 25;
        float sum = 0.f;
#pragma unroll
        for (int dt = 0; dt < 4; ++dt) {
            float a = pb2l[g];
            for (int f = 0; f < NF_; ++f)
                a = fmaf(pwcl[g * 40 + f], dwo[f * 100 + tp * 4 + dt], a);
            sum += elu_f(a);
        }
        po[e] = sum * 0.25f;
    }
    __syncthreads();
    for (int e = tid; e < 400; e += 256) {
        const int tp = e >> 4;
        const int k = e & 15;
        float a = bpl[k];
        for (int g = 0; g < 80; ++g)
            a = fmaf(WPl[k * 80 + g], po[g * 25 + tp], a);
        xp[(b * TP_ + tp0 + tp) * K_ + k] = a;
    }
}

// Sequential 500-step scan, DPP-only cross-lane, software-pipelined by one
// step. 4 blocks x 1 wave; each wave = 4 batches x 16 k.
__global__ __launch_bounds__(64, 1) void k3_scan(
    const float* __restrict__ xp, const float* __restrict__ M0,
    const float* __restrict__ M1, const float* __restrict__ wx1,
    const float* __restrict__ b1, const float* __restrict__ ln0_g,
    const float* __restrict__ ln0_b, const float* __restrict__ ln1_g,
    const float* __restrict__ ln1_b, float* __restrict__ out) {
    const int lane = threadIdx.x;
    const int b = blockIdx.x * 4 + (lane >> 4);
    const int k = lane & 15;

    int pidx[16];
    ALLGATHER16I(pidx, k);

    float M0r[16], M1r[16], w1r[16];
#pragma unroll
    for (int j = 0; j < 16; ++j) {
        M0r[j] = M0[k * 16 + pidx[j]];
        M1r[j] = M1[k * 16 + pidx[j]];
        w1r[j] = wx1[k * 16 + pidx[j]];
    }
    const float b1r = b1[k];
    const float g0 = ln0_g[k], be0 = ln0_b[k];
    const float g1 = ln1_g[k], be1 = ln1_b[k];
    const float* xpb = xp + b * TP_ * K_ + k;

    float x0 = xpb[0];
    {
        float s1 = x0, s2 = x0 * x0;
        RSUM16(s1);
        RSUM16(s2);
        const float mu = s1 * 0.0625f;
        const float var = s2 * 0.0625f - mu * mu;
        const float r = rsqrtf(var + 1e-5f);
        x0 = tanh_f((x0 - mu) * r * g0 + be0);
    }
    float h0c = x0;
    float h1c = 0.f;

    float xn[4];
    xn[1] = xpb[1 * K_];
    xn[2] = xpb[2 * K_];
    xn[3] = xpb[3 * K_];
    xn[0] = xpb[4 * K_];

    for (int t = 0; t < TP_; ++t) {
        float h0g[16], h1g[16];
        ALLGATHER16F(h0g, h0c);
        ALLGATHER16F(h1g, h1c);
        const int slot = (t + 1) & 3;
        const float xv = xn[slot];
        int tf = t + 5;
        if (tf > TP_ - 1) tf = TP_ - 1;
        xn[slot] = xpb[tf * K_];

        float q0 = b1r, q1 = 0.f, q2 = 0.f, q3 = 0.f;
#pragma unroll
        for (int j = 0; j < 16; j += 4) {
            q0 = fmaf(w1r[j],     h0g[j],     q0);
            q1 = fmaf(w1r[j + 1], h0g[j + 1], q1);
            q2 = fmaf(w1r[j + 2], h0g[j + 2], q2);
            q3 = fmaf(w1r[j + 3], h0g[j + 3], q3);
        }
#pragma unroll
        for (int j = 0; j < 16; j += 4) {
            q0 = fmaf(M1r[j],     h1g[j],     q0);
            q1 = fmaf(M1r[j + 1], h1g[j + 1], q1);
            q2 = fmaf(M1r[j + 2], h1g[j + 2], q2);
            q3 = fmaf(M1r[j + 3], h1g[j + 3], q3);
        }
        const float pre1 = (q0 + q1) + (q2 + q3);
        float u1 = pre1, u2 = pre1 * pre1;
        RSUM16(u1);
        RSUM16(u2);
        const float mu1 = u1 * 0.0625f;
        const float var1 = u2 * 0.0625f - mu1 * mu1;
        const float r1 = rsqrtf(var1 + 1e-5f);
        const float h1n = tanh_f((pre1 - mu1) * r1 * g1 + be1);

        float p0 = xv, p1 = 0.f, p2 = 0.f, p3 = 0.f;
#pragma unroll
        for (int j = 0; j < 16; j += 4) {
            p0 = fmaf(M0r[j],     h0g[j],     p0);
            p1 = fmaf(M0r[j + 1], h0g[j + 1], p1);
            p2 = fmaf(M0r[j + 2], h0g[j + 2], p2);
            p3 = fmaf(M0r[j + 3], h0g[j + 3], p3);
        }
        const float pre0 = (p0 + p1) + (p2 + p3);
        float s1 = pre0, s2 = pre0 * pre0;
        RSUM16(s1);
        RSUM16(s2);
        const float mu0 = s1 * 0.0625f;
        const float var0 = s2 * 0.0625f - mu0 * mu0;
        const float r0 = rsqrtf(var0 + 1e-5f);
        const float h0n = tanh_f((pre0 - mu0) * r0 * g0 + be0);

        h1c = h1n;
        h0c = h0n;
    }
    out[b * K_ + k] = h1c;              // Z
    if (k == 0) out[256 + b] = 1.0f;    // alpha = softmax over size-1 axis
}

extern "C" void kernel_launch(void* const* d_in, const int* in_sizes, int n_in,
                              void* d_out, int out_size, void* d_ws, size_t ws_size,
                              hipStream_t stream) {
    const float* x       = (const float*)d_in[0];
    const float* sconv_w = (const float*)d_in[7];
    const float* sbn_g   = (const float*)d_in[9];
    const float* sbn_v   = (const float*)d_in[12];
    const float* dw_w    = (const float*)d_in[13];
    const float* dw_b    = (const float*)d_in[14];
    const float* wx1     = (const float*)d_in[29];
    const float* b1      = (const float*)d_in[32];
    const float* ln0_g   = (const float*)d_in[27];
    const float* ln0_b   = (const float*)d_in[28];
    const float* ln1_g   = (const float*)d_in[33];
    const float* ln1_b   = (const float*)d_in[34];
    float* ws = (float*)d_ws;
    float* out = (float*)d_out;

    P0 p;
    p.tconv_w = (const float*)d_in[1]; p.tconv_b = (const float*)d_in[2];
    p.tbn_g = (const float*)d_in[3]; p.tbn_b = (const float*)d_in[4];
    p.tbn_m = (const float*)d_in[5]; p.tbn_v = (const float*)d_in[6];
    p.sconv_b = (const float*)d_in[8];
    p.sbn_g = sbn_g; p.sbn_b = (const float*)d_in[10];
    p.sbn_m = (const float*)d_in[11]; p.sbn_v = sbn_v;
    p.pw_w = (const float*)d_in[15]; p.pw_b = (const float*)d_in[16];
    p.pbn_g = (const float*)d_in[17]; p.pbn_b = (const float*)d_in[18];
    p.pbn_m = (const float*)d_in[19]; p.pbn_v = (const float*)d_in[20];
    p.proj_w = (const float*)d_in[21]; p.proj_b = (const float*)d_in[22];
    p.wx0 = (const float*)d_in[23]; p.b0 = (const float*)d_in[26];
    p.L0 = (const float*)d_in[24]; p.ll0 = (const float*)d_in[25];
    p.L1 = (const float*)d_in[30]; p.ll1 = (const float*)d_in[31];
    p.ws = ws;

    unsigned short* w2b = (unsigned short*)(ws + OFF_W2U);

    k0a_setup<<<dim3(8), dim3(256), 0, stream>>>(p);
    k0b_repack<<<dim3(194), dim3(256), 0, stream>>>(sconv_w, sbn_g, sbn_v, w2b);
    k1z<<<dim3(1250), dim3(256), 0, stream>>>((float4*)(ws + OFF_S2R));
    k1_mfma<<<dim3(1024), dim3(256), 0, stream>>>(x, ws + OFF_W1C, ws + OFF_TB2,
                                                  w2b, ws + OFF_S2R);
    k2_dwpw<<<dim3(320), dim3(256), 0, stream>>>(ws + OFF_S2R, ws + OFF_SB2,
                                                 dw_w, dw_b, ws + OFF_PWC,
                                                 ws + OFF_PB2, ws + OFF_WP, ws + OFF_BP,
                                                 ws + OFF_XP);
    k3_scan<<<dim3(4), dim3(64), 0, stream>>>(ws + OFF_XP, ws + OFF_M0, ws + OFF_M1,
                                              wx1, b1, ln0_g, ln0_b, ln1_g, ln1_b, out);
}

// Round 7
// 478.687 us; speedup vs baseline: 3.5495x; 1.2004x over previous
//
#include <hip/hip_runtime.h>
#include <math.h>

#define B_ 16
#define C_ 129
#define T_ 2000
#define NF_ 40
#define ED_ 64
#define K_ 16
#define TP_ 500

// workspace float offsets
#define OFF_SB2 1040     // 40     folded sconv bias
#define OFF_PWC 1088     // 3200   pw weights * pbn scale
#define OFF_PB2 4288     // 80     folded pw bias
#define OFF_WP  4368     // 1280   wx0 @ proj_w  (16x80)
#define OFF_BP  5648     // 16     wx0 @ proj_b + b0
#define OFF_M0  5664     // 256    L0@L0.T - exp(ll0) I
#define OFF_M1  5920     // 256    L1@L1.T - exp(ll1) I
#define OFF_W1A 6224     // 768 floats = 1536 bf16: tconv A-frag prepack (3 mt x 64 lanes x 8)
#define OFF_W2U 8192     // bf16 A-frag prepack of sconv weights: 396288 ushort
#define OFF_XP  1495040  // 16*500*16  per-step cell0 input projection
#define OFF_S2R 1623040  // 1.28M  raw sconv accumulator (atomicAdd target)

typedef __attribute__((ext_vector_type(8))) short s8v;
typedef __attribute__((ext_vector_type(4))) float f4v;

#define XROW 292         // xs row stride: 256 t + 24 halo + 12 left pad

__device__ __forceinline__ float elu_f(float x) {
    return x > 0.f ? x : (__expf(x) - 1.f);
}
__device__ __forceinline__ float tanh_f(float x) {
    float xc = fminf(fmaxf(x, -15.f), 15.f);
    float e2 = __expf(2.f * xc);
    return 1.f - 2.f / (e2 + 1.f);
}
// round-half-up fp32 -> bf16
__device__ __forceinline__ unsigned bfr(float v) {
    return (__float_as_uint(v) + 0x8000u) >> 16;
}

// DPP helpers (k3): row_ror:n ctrl = 0x120+n, rows of 16 lanes.
#define DPPF(v, ctrl) __int_as_float(__builtin_amdgcn_update_dpp( \
    0, __float_as_int(v), (ctrl), 0xF, 0xF, false))
#define DPPI(v, ctrl) __builtin_amdgcn_update_dpp(0, (v), (ctrl), 0xF, 0xF, false)

#define ALLGATHER16F(dst, src) do {        \
    dst[0] = (src);                        \
    dst[1] = DPPF(dst[0], 0x121);          \
    dst[2] = DPPF(dst[0], 0x122);          \
    dst[3] = DPPF(dst[1], 0x122);          \
    dst[4] = DPPF(dst[0], 0x124);          \
    dst[5] = DPPF(dst[1], 0x124);          \
    dst[6] = DPPF(dst[2], 0x124);          \
    dst[7] = DPPF(dst[3], 0x124);          \
    dst[8] = DPPF(dst[0], 0x128);          \
    dst[9] = DPPF(dst[1], 0x128);          \
    dst[10] = DPPF(dst[2], 0x128);         \
    dst[11] = DPPF(dst[3], 0x128);         \
    dst[12] = DPPF(dst[4], 0x128);         \
    dst[13] = DPPF(dst[5], 0x128);         \
    dst[14] = DPPF(dst[6], 0x128);         \
    dst[15] = DPPF(dst[7], 0x128);         \
} while (0)

#define ALLGATHER16I(dst, src) do {        \
    dst[0] = (src);                        \
    dst[1] = DPPI(dst[0], 0x121);          \
    dst[2] = DPPI(dst[0], 0x122);          \
    dst[3] = DPPI(dst[1], 0x122);          \
    dst[4] = DPPI(dst[0], 0x124);          \
    dst[5] = DPPI(dst[1], 0x124);          \
    dst[6] = DPPI(dst[2], 0x124);          \
    dst[7] = DPPI(dst[3], 0x124);          \
    dst[8] = DPPI(dst[0], 0x128);          \
    dst[9] = DPPI(dst[1], 0x128);          \
    dst[10] = DPPI(dst[2], 0x128);         \
    dst[11] = DPPI(dst[3], 0x128);         \
    dst[12] = DPPI(dst[4], 0x128);         \
    dst[13] = DPPI(dst[5], 0x128);         \
    dst[14] = DPPI(dst[6], 0x128);         \
    dst[15] = DPPI(dst[7], 0x128);         \
} while (0)

#define RSUM16(s) do {                     \
    s += DPPF(s, 0x128);                   \
    s += DPPF(s, 0x124);                   \
    s += DPPF(s, 0x122);                   \
    s += DPPF(s, 0x121);                   \
} while (0)

struct P0 {
    const float *tconv_w, *tconv_b, *tbn_g, *tbn_b, *tbn_m, *tbn_v;
    const float *sconv_b, *sbn_g, *sbn_b, *sbn_m, *sbn_v;
    const float *pw_w, *pw_b, *pbn_g, *pbn_b, *pbn_m, *pbn_v;
    const float *proj_w, *proj_b, *wx0, *b0, *L0, *ll0, *L1, *ll1;
    float* ws;
};

__global__ __launch_bounds__(256) void k0a_setup(P0 p) {
    const int tid = blockIdx.x * 256 + threadIdx.x;
    const int stride = gridDim.x * 256;
    float* ws = p.ws;
    const float eps = 1e-5f;
    // tconv A-frag prepack (bf16): A[m=f][k=tap], K=32; tap 25 = folded bias
    // (B supplies 1.0 there); taps 26..31 and f>=40 are zero.
    for (int e = tid; e < 192; e += stride) {
        const int mt = e >> 6, L = e & 63;
        const int f = mt * 16 + (L & 15);
        float inv = 0.f, bias = 0.f;
        if (f < NF_) {
            inv = p.tbn_g[f] / sqrtf(p.tbn_v[f] + eps);
            bias = p.tconv_b[f] * inv + p.tbn_b[f] - p.tbn_m[f] * inv;
        }
        unsigned short* dst = ((unsigned short*)(ws + OFF_W1A)) + e * 8;
#pragma unroll
        for (int j = 0; j < 8; ++j) {
            const int k = (L >> 4) * 8 + j;
            float v = 0.f;
            if (f < NF_) {
                if (k < 25) v = p.tconv_w[f * 25 + k] * inv;
                else if (k == 25) v = bias;
            }
            dst[j] = (unsigned short)bfr(v);
        }
    }
    for (int f = tid; f < NF_; f += stride) {
        const float sinv = p.sbn_g[f] / sqrtf(p.sbn_v[f] + eps);
        ws[OFF_SB2 + f] = p.sconv_b[f] * sinv + p.sbn_b[f] - p.sbn_m[f] * sinv;
    }
    for (int e = tid; e < 3200; e += stride) {
        const int g = e / 40;
        const float pinv = p.pbn_g[g] / sqrtf(p.pbn_v[g] + eps);
        ws[OFF_PWC + e] = p.pw_w[e] * pinv;
    }
    for (int g = tid; g < 80; g += stride) {
        const float pinv = p.pbn_g[g] / sqrtf(p.pbn_v[g] + eps);
        ws[OFF_PB2 + g] = p.pw_b[g] * pinv + p.pbn_b[g] - p.pbn_m[g] * pinv;
    }
    for (int e = tid; e < 1280; e += stride) {
        const int k = e / 80, g = e - k * 80;
        float a = 0.f;
        for (int ee = 0; ee < ED_; ++ee)
            a = fmaf(p.wx0[k * ED_ + ee], p.proj_w[ee * 80 + g], a);
        ws[OFF_WP + e] = a;
    }
    for (int k = tid; k < K_; k += stride) {
        float a = p.b0[k];
        for (int ee = 0; ee < ED_; ++ee)
            a = fmaf(p.wx0[k * ED_ + ee], p.proj_b[ee], a);
        ws[OFF_BP + k] = a;
    }
    for (int e = tid; e < 256; e += stride) {
        const int k = e >> 4, j = e & 15;
        float a0 = 0.f, a1 = 0.f;
        for (int i = 0; i < 16; ++i) {
            a0 = fmaf(p.L0[k * 16 + i], p.L0[j * 16 + i], a0);
            a1 = fmaf(p.L1[k * 16 + i], p.L1[j * 16 + i], a1);
        }
        if (k == j) { a0 -= expf(p.ll0[0]); a1 -= expf(p.ll1[0]); }
        ws[OFF_M0 + e] = a0;
        ws[OFF_M1 + e] = a1;
    }
}

// Prepack sconv weights * sbn scale into bf16 MFMA A-fragment order (unchanged
// from round 6): g = mt*16 + (L&15), f = kc*32 + (L>>4)*8 + j, zero-padded.
__global__ __launch_bounds__(256) void k0b_repack(
    const float* __restrict__ sconv_w, const float* __restrict__ sbn_g,
    const float* __restrict__ sbn_v, unsigned short* __restrict__ w2b) {
    const int e = blockIdx.x * 256 + threadIdx.x;
    if (e >= C_ * 3 * 2 * 64) return;
    const int c = e / 384;
    int r = e - c * 384;
    const int mt = r >> 7; r &= 127;
    const int kc = r >> 6;
    const int lane = r & 63;
    const int g = mt * 16 + (lane & 15);
    const float sinv = (g < NF_) ? sbn_g[g] * rsqrtf(sbn_v[g] + 1e-5f) : 0.f;
    unsigned short o[8];
#pragma unroll
    for (int j = 0; j < 8; ++j) {
        const int f = kc * 32 + (lane >> 4) * 8 + j;
        float v = 0.f;
        if (g < NF_ && f < NF_) v = sconv_w[g * (NF_ * C_) + f * C_ + c] * sinv;
        o[j] = (unsigned short)bfr(v);
    }
    unsigned short* dst = w2b + (size_t)e * 8;
#pragma unroll
    for (int j = 0; j < 8; ++j) dst[j] = o[j];
}

// zero the raw accumulator (ws is re-poisoned 0xAA before every launch)
__global__ __launch_bounds__(256) void k1z(float4* __restrict__ p) {
    const int i = blockIdx.x * 256 + threadIdx.x;
    if (i < 320000) p[i] = make_float4(0.f, 0.f, 0.f, 0.f);
}

// Both convs on MFMA. tconv: A = w1 (40x32 padded, bias in tap 25),
// B = Hankel(x) built per-lane from 8 consecutive LDS reads. C-layout
// (col=t, row=f) pairs (f, f+1) in-lane -> pack bf16 + write V panel
// (rows nt*8+oct, 16B block n, pair slot = 2(q&1)+(r>>1): <=2-way banks).
// sconv: unchanged round-6 reader (b128 B-frags + 24 MFMA).
__global__ __launch_bounds__(256, 3) void k1_mfma(
    const float* __restrict__ x, const unsigned short* __restrict__ w1a,
    const unsigned short* __restrict__ w2b, float* __restrict__ s2raw) {
    __shared__ float xs[17 * XROW];
    __shared__ unsigned int vsI[8192];      // 4 waves x 32 rows x 64 words

    const int tid = threadIdx.x;
    const int split = blockIdx.x & 7;
    const int tile = (blockIdx.x >> 3) & 7;
    const int b = blockIdx.x >> 6;
    const int c0 = (split * C_) >> 3;
    const int c1 = ((split + 1) * C_) >> 3;
    const int cc = c1 - c0;
    const int t0 = tile << 8;
    const int w = tid >> 6;
    const int lane = tid & 63;
    const int n = lane & 15;
    const int q = lane >> 4;
    const int qh = q >> 1;
    const int q1_2 = (q & 1) * 2;
    const bool q3 = (q == 3);
    const int wb = w << 11;
    const int w64 = w << 6;
    const int ln8 = n + q * 8;

    for (int i = tid; i < 8192; i += 256) vsI[i] = 0u;
    for (int e = tid; e < cc * XROW; e += 256) {
        const int cl = e / XROW;
        const int i = e - cl * XROW;
        const int t = t0 - 12 + i;
        float v = 0.f;
        if ((unsigned)t < (unsigned)T_) v = x[(b * C_ + c0 + cl) * T_ + t];
        xs[e] = v;
    }
    __syncthreads();

    // tconv A-frags (wave-uniform, loaded once)
    const s8v* w1a8 = (const s8v*)w1a;
    s8v wA[3];
#pragma unroll
    for (int mt = 0; mt < 3; ++mt) wA[mt] = w1a8[mt * 64 + lane];

    f4v acc[4][3];
#pragma unroll
    for (int nt = 0; nt < 4; ++nt)
#pragma unroll
        for (int mt = 0; mt < 3; ++mt) acc[nt][mt] = (f4v)0.f;

    const s8v* w2b8 = (const s8v*)w2b;
    const f4v z4 = (f4v)0.f;

    for (int cl = 0; cl < cc; ++cl) {
        const int c = c0 + cl;
        // prefetch sconv A-frags for this channel (6 x 16B, coalesced)
        s8v af[3][2];
#pragma unroll
        for (int mt = 0; mt < 3; ++mt)
#pragma unroll
            for (int kc = 0; kc < 2; ++kc)
                af[mt][kc] = w2b8[((c * 3 + mt) * 2 + kc) * 64 + lane];

        const float* xrow = &xs[cl * XROW + w64 + ln8];

        // tconv via MFMA, per t-subtile; ELU + pack + V-panel write
#pragma unroll
        for (int nt = 0; nt < 4; ++nt) {
            float bx[8];
#pragma unroll
            for (int j = 0; j < 8; ++j) bx[j] = xrow[nt * 16 + j];
            if (q3) bx[1] = 1.0f;           // k=25: bias channel
            unsigned pw_[4];
#pragma unroll
            for (int jj = 0; jj < 4; ++jj)
                pw_[jj] = bfr(bx[2 * jj]) |
                    ((__float_as_uint(bx[2 * jj + 1]) + 0x8000u) & 0xFFFF0000u);
            const s8v bh = *(const s8v*)pw_;
#pragma unroll
            for (int mt = 0; mt < 3; ++mt) {
                const f4v vT = __builtin_amdgcn_mfma_f32_16x16x32_bf16(
                    wA[mt], bh, z4, 0, 0, 0);
                const float e0 = elu_f(vT[0]);
                const float e1 = elu_f(vT[1]);
                const float e2 = elu_f(vT[2]);
                const float e3 = elu_f(vT[3]);
                const unsigned lo = bfr(e0) |
                    ((__float_as_uint(e1) + 0x8000u) & 0xFFFF0000u);
                const unsigned hi = bfr(e2) |
                    ((__float_as_uint(e3) + 0x8000u) & 0xFFFF0000u);
                const int base = wb + ((nt * 8 + 2 * mt + qh) << 6) + (n << 2) + q1_2;
                vsI[base] = lo;
                vsI[base + 1] = hi;
            }
        }
        __builtin_amdgcn_wave_barrier();

        // sconv MFMA (round-6 reader, unchanged)
#pragma unroll
        for (int nt = 0; nt < 4; ++nt) {
            const s8v b0 = *(const s8v*)&vsI[wb + ((nt * 8 + q) << 6) + (n << 2)];
            const s8v b1 = *(const s8v*)&vsI[wb + ((nt * 8 + 4 + q) << 6) + (n << 2)];
#pragma unroll
            for (int mt = 0; mt < 3; ++mt) {
                acc[nt][mt] = __builtin_amdgcn_mfma_f32_16x16x32_bf16(
                    af[mt][0], b0, acc[nt][mt], 0, 0, 0);
                acc[nt][mt] = __builtin_amdgcn_mfma_f32_16x16x32_bf16(
                    af[mt][1], b1, acc[nt][mt], 0, 0, 0);
            }
        }
        __builtin_amdgcn_wave_barrier();
    }

    // epilogue: C/D layout col=lane&15 (t), row=quad*4+reg (g)
#pragma unroll
    for (int nt = 0; nt < 4; ++nt) {
        const int t = t0 + w * 64 + nt * 16 + n;
        if (t >= T_) continue;
#pragma unroll
        for (int mt = 0; mt < 3; ++mt) {
#pragma unroll
            for (int r = 0; r < 4; ++r) {
                const int g = mt * 16 + q * 4 + r;
                if (g < NF_)
                    atomicAdd(&s2raw[(b * NF_ + g) * T_ + t], acc[nt][mt][r]);
            }
        }
    }
}

// Fused: bias+ELU on s2raw at stage time, depthwise(15) + pointwise(80x40)
// + BN + ELU + pool4 + (proj∘wx0) -> xp[b][tp][k]
__global__ __launch_bounds__(256) void k2_dwpw(
    const float* __restrict__ s2raw, const float* __restrict__ sb2,
    const float* __restrict__ dw_w, const float* __restrict__ dw_b,
    const float* __restrict__ pwc, const float* __restrict__ pb2,
    const float* __restrict__ WP, const float* __restrict__ bp,
    float* __restrict__ xp) {
    __shared__ float st[NF_ * 114];
    __shared__ float dwo[NF_ * 100];
    __shared__ float dwwl[NF_ * 15];
    __shared__ float dwbl[NF_];
    __shared__ float pwcl[80 * 40];
    __shared__ float pb2l[80];
    __shared__ float WPl[K_ * 80];
    __shared__ float bpl[K_];
    __shared__ float po[80 * 25];
    const int tid = threadIdx.x;
    const int b = blockIdx.x / 20;
    const int tp0 = (blockIdx.x % 20) * 25;
    const int tbase = tp0 * 4 - 7;
    for (int e = tid; e < NF_ * 114; e += 256) {
        const int f = e / 114;
        const int i = e - f * 114;
        const int t = tbase + i;
        float v = 0.f;
        if ((unsigned)t < (unsigned)T_)
            v = elu_f(s2raw[(b * NF_ + f) * T_ + t] + sb2[f]);
        st[e] = v;
    }
    for (int e = tid; e < 600; e += 256) dwwl[e] = dw_w[e];
    for (int e = tid; e < 3200; e += 256) pwcl[e] = pwc[e];
    for (int e = tid; e < 1280; e += 256) WPl[e] = WP[e];
    if (tid < NF_) dwbl[tid] = dw_b[tid];
    if (tid < 80) pb2l[tid] = pb2[tid];
    if (tid < K_) bpl[tid] = bp[tid];
    __syncthreads();
    for (int e = tid; e < 4000; e += 256) {
        const int f = e / 100;
        const int tq = e - f * 100;
        float a = dwbl[f];
#pragma unroll
        for (int kk = 0; kk < 15; ++kk)
            a = fmaf(dwwl[f * 15 + kk], st[f * 114 + tq + kk], a);
        dwo[e] = a;
    }
    __syncthreads();
    for (int e = tid; e < 2000; e += 256) {
        const int g = e / 25;
        const int tp = e - g * 25;
        float sum = 0.f;
#pragma unroll
        for (int dt = 0; dt < 4; ++dt) {
            float a = pb2l[g];
            for (int f = 0; f < NF_; ++f)
                a = fmaf(pwcl[g * 40 + f], dwo[f * 100 + tp * 4 + dt], a);
            sum += elu_f(a);
        }
        po[e] = sum * 0.25f;
    }
    __syncthreads();
    for (int e = tid; e < 400; e += 256) {
        const int tp = e >> 4;
        const int k = e & 15;
        float a = bpl[k];
        for (int g = 0; g < 80; ++g)
            a = fmaf(WPl[k * 80 + g], po[g * 25 + tp], a);
        xp[(b * TP_ + tp0 + tp) * K_ + k] = a;
    }
}

// Sequential 500-step scan, DPP-only cross-lane, software-pipelined by one
// step. 4 blocks x 1 wave; each wave = 4 batches x 16 k.
__global__ __launch_bounds__(64, 1) void k3_scan(
    const float* __restrict__ xp, const float* __restrict__ M0,
    const float* __restrict__ M1, const float* __restrict__ wx1,
    const float* __restrict__ b1, const float* __restrict__ ln0_g,
    const float* __restrict__ ln0_b, const float* __restrict__ ln1_g,
    const float* __restrict__ ln1_b, float* __restrict__ out) {
    const int lane = threadIdx.x;
    const int b = blockIdx.x * 4 + (lane >> 4);
    const int k = lane & 15;

    int pidx[16];
    ALLGATHER16I(pidx, k);

    float M0r[16], M1r[16], w1r[16];
#pragma unroll
    for (int j = 0; j < 16; ++j) {
        M0r[j] = M0[k * 16 + pidx[j]];
        M1r[j] = M1[k * 16 + pidx[j]];
        w1r[j] = wx1[k * 16 + pidx[j]];
    }
    const float b1r = b1[k];
    const float g0 = ln0_g[k], be0 = ln0_b[k];
    const float g1 = ln1_g[k], be1 = ln1_b[k];
    const float* xpb = xp + b * TP_ * K_ + k;

    float x0 = xpb[0];
    {
        float s1 = x0, s2 = x0 * x0;
        RSUM16(s1);
        RSUM16(s2);
        const float mu = s1 * 0.0625f;
        const float var = s2 * 0.0625f - mu * mu;
        const float r = rsqrtf(var + 1e-5f);
        x0 = tanh_f((x0 - mu) * r * g0 + be0);
    }
    float h0c = x0;
    float h1c = 0.f;

    float xn[4];
    xn[1] = xpb[1 * K_];
    xn[2] = xpb[2 * K_];
    xn[3] = xpb[3 * K_];
    xn[0] = xpb[4 * K_];

    for (int t = 0; t < TP_; ++t) {
        float h0g[16], h1g[16];
        ALLGATHER16F(h0g, h0c);
        ALLGATHER16F(h1g, h1c);
        const int slot = (t + 1) & 3;
        const float xv = xn[slot];
        int tf = t + 5;
        if (tf > TP_ - 1) tf = TP_ - 1;
        xn[slot] = xpb[tf * K_];

        float q0 = b1r, q1 = 0.f, q2 = 0.f, q3 = 0.f;
#pragma unroll
        for (int j = 0; j < 16; j += 4) {
            q0 = fmaf(w1r[j],     h0g[j],     q0);
            q1 = fmaf(w1r[j + 1], h0g[j + 1], q1);
            q2 = fmaf(w1r[j + 2], h0g[j + 2], q2);
            q3 = fmaf(w1r[j + 3], h0g[j + 3], q3);
        }
#pragma unroll
        for (int j = 0; j < 16; j += 4) {
            q0 = fmaf(M1r[j],     h1g[j],     q0);
            q1 = fmaf(M1r[j + 1], h1g[j + 1], q1);
            q2 = fmaf(M1r[j + 2], h1g[j + 2], q2);
            q3 = fmaf(M1r[j + 3], h1g[j + 3], q3);
        }
        const float pre1 = (q0 + q1) + (q2 + q3);
        float u1 = pre1, u2 = pre1 * pre1;
        RSUM16(u1);
        RSUM16(u2);
        const float mu1 = u1 * 0.0625f;
        const float var1 = u2 * 0.0625f - mu1 * mu1;
        const float r1 = rsqrtf(var1 + 1e-5f);
        const float h1n = tanh_f((pre1 - mu1) * r1 * g1 + be1);

        float p0 = xv, p1 = 0.f, p2 = 0.f, p3 = 0.f;
#pragma unroll
        for (int j = 0; j < 16; j += 4) {
            p0 = fmaf(M0r[j],     h0g[j],     p0);
            p1 = fmaf(M0r[j + 1], h0g[j + 1], p1);
            p2 = fmaf(M0r[j + 2], h0g[j + 2], p2);
            p3 = fmaf(M0r[j + 3], h0g[j + 3], p3);
        }
        const float pre0 = (p0 + p1) + (p2 + p3);
        float s1 = pre0, s2 = pre0 * pre0;
        RSUM16(s1);
        RSUM16(s2);
        const float mu0 = s1 * 0.0625f;
        const float var0 = s2 * 0.0625f - mu0 * mu0;
        const float r0 = rsqrtf(var0 + 1e-5f);
        const float h0n = tanh_f((pre0 - mu0) * r0 * g0 + be0);

        h1c = h1n;
        h0c = h0n;
    }
    out[b * K_ + k] = h1c;              // Z
    if (k == 0) out[256 + b] = 1.0f;    // alpha = softmax over size-1 axis
}

extern "C" void kernel_launch(void* const* d_in, const int* in_sizes, int n_in,
                              void* d_out, int out_size, void* d_ws, size_t ws_size,
                              hipStream_t stream) {
    const float* x       = (const float*)d_in[0];
    const float* sconv_w = (const float*)d_in[7];
    const float* sbn_g   = (const float*)d_in[9];
    const float* sbn_v   = (const float*)d_in[12];
    const float* dw_w    = (const float*)d_in[13];
    const float* dw_b    = (const float*)d_in[14];
    const float* wx1     = (const float*)d_in[29];
    const float* b1      = (const float*)d_in[32];
    const float* ln0_g   = (const float*)d_in[27];
    const float* ln0_b   = (const float*)d_in[28];
    const float* ln1_g   = (const float*)d_in[33];
    const float* ln1_b   = (const float*)d_in[34];
    float* ws = (float*)d_ws;
    float* out = (float*)d_out;

    P0 p;
    p.tconv_w = (const float*)d_in[1]; p.tconv_b = (const float*)d_in[2];
    p.tbn_g = (const float*)d_in[3]; p.tbn_b = (const float*)d_in[4];
    p.tbn_m = (const float*)d_in[5]; p.tbn_v = (const float*)d_in[6];
    p.sconv_b = (const float*)d_in[8];
    p.sbn_g = sbn_g; p.sbn_b = (const float*)d_in[10];
    p.sbn_m = (const float*)d_in[11]; p.sbn_v = sbn_v;
    p.pw_w = (const float*)d_in[15]; p.pw_b = (const float*)d_in[16];
    p.pbn_g = (const float*)d_in[17]; p.pbn_b = (const float*)d_in[18];
    p.pbn_m = (const float*)d_in[19]; p.pbn_v = (const float*)d_in[20];
    p.proj_w = (const float*)d_in[21]; p.proj_b = (const float*)d_in[22];
    p.wx0 = (const float*)d_in[23]; p.b0 = (const float*)d_in[26];
    p.L0 = (const float*)d_in[24]; p.ll0 = (const float*)d_in[25];
    p.L1 = (const float*)d_in[30]; p.ll1 = (const float*)d_in[31];
    p.ws = ws;

    unsigned short* w2b = (unsigned short*)(ws + OFF_W2U);
    unsigned short* w1a = (unsigned short*)(ws + OFF_W1A);

    k0a_setup<<<dim3(8), dim3(256), 0, stream>>>(p);
    k0b_repack<<<dim3(194), dim3(256), 0, stream>>>(sconv_w, sbn_g, sbn_v, w2b);
    k1z<<<dim3(1250), dim3(256), 0, stream>>>((float4*)(ws + OFF_S2R));
    k1_mfma<<<dim3(1024), dim3(256), 0, stream>>>(x, w1a, w2b, ws + OFF_S2R);
    k2_dwpw<<<dim3(320), dim3(256), 0, stream>>>(ws + OFF_S2R, ws + OFF_SB2,
                                                 dw_w, dw_b, ws + OFF_PWC,
                                                 ws + OFF_PB2, ws + OFF_WP, ws + OFF_BP,
                                                 ws + OFF_XP);
    k3_scan<<<dim3(4), dim3(64), 0, stream>>>(ws + OFF_XP, ws + OFF_M0, ws + OFF_M1,
                                              wx1, b1, ln0_g, ln0_b, ln1_g, ln1_b, out);
}